// Round 1
// baseline (689.538 us; speedup 1.0000x reference)
//
#include <hip/hip_runtime.h>

#define NN 50000
#define NE 1600000
#define DD 128
#define HH 128
#define CC 10
#define GG 512
#define LRELU_A 0.05f
#define BN_EPS 1e-5f

// ---------------- stats: global sum & sumsq of x_in ----------------
__global__ __launch_bounds__(256) void k_stats(const float* __restrict__ x,
                                               double* __restrict__ st) {
    const int M4 = NN * DD / 4;
    double s = 0.0, ss = 0.0;
    for (int i = blockIdx.x * blockDim.x + threadIdx.x; i < M4;
         i += gridDim.x * blockDim.x) {
        float4 v = reinterpret_cast<const float4*>(x)[i];
        s  += (double)v.x + (double)v.y + (double)v.z + (double)v.w;
        ss += (double)v.x * v.x + (double)v.y * v.y + (double)v.z * v.z +
              (double)v.w * v.w;
    }
    for (int d = 32; d; d >>= 1) { s += __shfl_down(s, d); ss += __shfl_down(ss, d); }
    __shared__ double ls[4], lss[4];
    int lane = threadIdx.x & 63, w = threadIdx.x >> 6;
    if (lane == 0) { ls[w] = s; lss[w] = ss; }
    __syncthreads();
    if (threadIdx.x == 0) {
        s  = ls[0] + ls[1] + ls[2] + ls[3];
        ss = lss[0] + lss[1] + lss[2] + lss[3];
        atomicAdd(&st[0], s);
        atomicAdd(&st[1], ss);
    }
}

// ---------------- finalize stats + per-output-row weight sums ----------------
__global__ __launch_bounds__(128) void k_finalize(const float* __restrict__ fc_w,
                                                  const double* __restrict__ st,
                                                  float* __restrict__ wsum,
                                                  float* __restrict__ musig) {
    int c = threadIdx.x;
    float s = 0.f;
    for (int k = 0; k < DD; ++k) s += fc_w[c * DD + k];
    wsum[c] = s;
    if (c == 0) {
        double M = (double)NN * DD;
        double mean = st[0] / M;
        double var  = (st[1] - st[0] * st[0] / M) / (M - 1.0);  // ddof=1
        musig[0] = (float)mean;
        musig[1] = (float)(1.0 / sqrt(var));
    }
}

// ---------------- edge histogram by src ----------------
__global__ __launch_bounds__(256) void k_hist(const int* __restrict__ src,
                                              int* __restrict__ cnt) {
    int e = blockIdx.x * 256 + threadIdx.x;
    if (e < NE) atomicAdd(&cnt[src[e]], 1);
}

// ---------------- single-block scan -> CSR offsets ----------------
__global__ __launch_bounds__(1024) void k_scan(const int* __restrict__ cnt,
                                               int* __restrict__ off,
                                               int* __restrict__ cursor) {
    __shared__ int part[1024];
    const int CH = (NN + 1023) / 1024;  // 49
    int t = threadIdx.x;
    int base = t * CH;
    int s = 0;
    for (int i = 0; i < CH; ++i)
        if (base + i < NN) s += cnt[base + i];
    part[t] = s;
    __syncthreads();
    for (int d = 1; d < 1024; d <<= 1) {
        int v = 0;
        if (t >= d) v = part[t - d];
        __syncthreads();
        if (t >= d) part[t] += v;
        __syncthreads();
    }
    int run = part[t] - s;  // exclusive prefix of this chunk
    for (int i = 0; i < CH; ++i) {
        int n = base + i;
        if (n < NN) {
            off[n] = run;
            cursor[n] = run;
            run += cnt[n];
        }
    }
    if (t == 1023) off[NN] = part[1023];
}

// ---------------- z = x_std @ fc_w^T (fused standardization) ----------------
#define PADX 132
__global__ __launch_bounds__(256) void k_gemm(const float* __restrict__ x,
                                              const float* __restrict__ w,
                                              const float* __restrict__ wsum,
                                              const float* __restrict__ musig,
                                              float* __restrict__ z) {
    __shared__ float xs[64][PADX];
    __shared__ float wt[128][128];  // wt[k][c] = w[c][k]
    int tid = threadIdx.x;
    int row0 = blockIdx.x * 64;

    // stage w transposed: 4096 float4 loads
    for (int i = tid; i < 128 * 32; i += 256) {
        int c = i >> 5;
        int m = i & 31;
        float4 v = reinterpret_cast<const float4*>(w)[c * 32 + m];
        int k4 = m << 2;
        wt[k4 + 0][c] = v.x;
        wt[k4 + 1][c] = v.y;
        wt[k4 + 2][c] = v.z;
        wt[k4 + 3][c] = v.w;
    }
    // stage x tile
    for (int i = tid; i < 64 * 32; i += 256) {
        int r = i >> 5;
        int m = i & 31;
        int gr = row0 + r;
        float4 v = (gr < NN) ? reinterpret_cast<const float4*>(x)[gr * 32 + m]
                             : make_float4(0.f, 0.f, 0.f, 0.f);
        *reinterpret_cast<float4*>(&xs[r][m << 2]) = v;
    }
    __syncthreads();

    int trow = tid >> 4, tcol = tid & 15;
    float acc[4][8];
    #pragma unroll
    for (int i = 0; i < 4; ++i)
        #pragma unroll
        for (int j = 0; j < 8; ++j) acc[i][j] = 0.f;

    for (int k = 0; k < 128; k += 4) {
        float4 xv[4];
        #pragma unroll
        for (int i = 0; i < 4; ++i)
            xv[i] = *reinterpret_cast<const float4*>(&xs[trow * 4 + i][k]);
        #pragma unroll
        for (int kk = 0; kk < 4; ++kk) {
            float4 w0 = *reinterpret_cast<const float4*>(&wt[k + kk][tcol * 8]);
            float4 w1 = *reinterpret_cast<const float4*>(&wt[k + kk][tcol * 8 + 4]);
            #pragma unroll
            for (int i = 0; i < 4; ++i) {
                float a = (kk == 0) ? xv[i].x
                        : (kk == 1) ? xv[i].y
                        : (kk == 2) ? xv[i].z : xv[i].w;
                acc[i][0] += a * w0.x; acc[i][1] += a * w0.y;
                acc[i][2] += a * w0.z; acc[i][3] += a * w0.w;
                acc[i][4] += a * w1.x; acc[i][5] += a * w1.y;
                acc[i][6] += a * w1.z; acc[i][7] += a * w1.w;
            }
        }
    }

    float mu = musig[0], isig = musig[1];
    #pragma unroll
    for (int i = 0; i < 4; ++i) {
        int gr = row0 + trow * 4 + i;
        if (gr >= NN) continue;
        int c0 = tcol * 8;
        float4 o0, o1;
        o0.x = (acc[i][0] - mu * wsum[c0 + 0]) * isig;
        o0.y = (acc[i][1] - mu * wsum[c0 + 1]) * isig;
        o0.z = (acc[i][2] - mu * wsum[c0 + 2]) * isig;
        o0.w = (acc[i][3] - mu * wsum[c0 + 3]) * isig;
        o1.x = (acc[i][4] - mu * wsum[c0 + 4]) * isig;
        o1.y = (acc[i][5] - mu * wsum[c0 + 5]) * isig;
        o1.z = (acc[i][6] - mu * wsum[c0 + 6]) * isig;
        o1.w = (acc[i][7] - mu * wsum[c0 + 7]) * isig;
        *reinterpret_cast<float4*>(&z[gr * HH + c0]) = o0;
        *reinterpret_cast<float4*>(&z[gr * HH + c0 + 4]) = o1;
    }
}

// ---------------- s1 = z@a1, s2 = z@a2 (one wave per node) ----------------
__global__ __launch_bounds__(256) void k_s1s2(const float* __restrict__ z,
                                              const float* __restrict__ a1,
                                              const float* __restrict__ a2,
                                              float* __restrict__ s1,
                                              float* __restrict__ s2) {
    int node = (blockIdx.x * 256 + threadIdx.x) >> 6;
    int lane = threadIdx.x & 63;
    if (node >= NN) return;
    float2 zv  = *reinterpret_cast<const float2*>(&z[node * HH + lane * 2]);
    float2 a1v = *reinterpret_cast<const float2*>(&a1[lane * 2]);
    float2 a2v = *reinterpret_cast<const float2*>(&a2[lane * 2]);
    float p1 = zv.x * a1v.x + zv.y * a1v.y;
    float p2 = zv.x * a2v.x + zv.y * a2v.y;
    for (int d = 32; d; d >>= 1) { p1 += __shfl_down(p1, d); p2 += __shfl_down(p2, d); }
    if (lane == 0) { s1[node] = p1; s2[node] = p2; }
}

// ---------------- scatter edges into CSR order (store dst only) ----------------
__global__ __launch_bounds__(256) void k_scatter(const int* __restrict__ src,
                                                 const int* __restrict__ dst,
                                                 int* __restrict__ cursor,
                                                 int* __restrict__ dst_s) {
    int e = blockIdx.x * 256 + threadIdx.x;
    if (e < NE) {
        int p = atomicAdd(&cursor[src[e]], 1);
        dst_s[p] = dst[e];
    }
}

// ---------------- aggregate: out[n] = relu( sum_e h*z[dst] / sum_e h ) ------
__global__ __launch_bounds__(256) void k_aggregate(const float* __restrict__ z,
                                                   const float* __restrict__ s1,
                                                   const float* __restrict__ s2,
                                                   const int* __restrict__ off,
                                                   const int* __restrict__ dst_s,
                                                   float* __restrict__ outb) {
    int node = (blockIdx.x * 256 + threadIdx.x) >> 6;
    int lane = threadIdx.x & 63;
    if (node >= NN) return;
    int j0 = off[node], j1 = off[node + 1];
    float s1n = s1[node];
    float acc0 = 0.f, acc1 = 0.f, hs = 0.f;
    for (int j = j0; j < j1; ++j) {
        int d = dst_s[j];
        float ev = s1n + s2[d];
        ev = (ev >= 0.f) ? ev : LRELU_A * ev;
        float h = __expf(ev);
        float2 zv = *reinterpret_cast<const float2*>(&z[d * HH + lane * 2]);
        acc0 += h * zv.x;
        acc1 += h * zv.y;
        hs += h;
    }
    float inv = (hs > 0.f) ? 1.f / hs : 0.f;
    float o0 = acc0 * inv, o1 = acc1 * inv;
    o0 = (o0 > 0.f) ? o0 : 0.f;
    o1 = (o1 > 0.f) ? o1 : 0.f;
    *reinterpret_cast<float2*>(&outb[node * HH + lane * 2]) = make_float2(o0, o1);
}

// ---------------- graph boundaries from sorted idx ----------------
__global__ __launch_bounds__(256) void k_bounds(const int* __restrict__ idx,
                                                int* __restrict__ start) {
    int n = blockIdx.x * 256 + threadIdx.x;
    if (n == 0) {
        for (int g = 0; g <= idx[0]; ++g) start[g] = 0;
    } else if (n < NN) {
        int a = idx[n - 1], b = idx[n];
        for (int g = a + 1; g <= b; ++g) start[g] = n;
    } else if (n == NN) {
        int a = idx[NN - 1];
        for (int g = a + 1; g <= GG; ++g) start[g] = NN;
    }
}

// ---------------- sum pooling per graph ----------------
__global__ __launch_bounds__(128) void k_pool(const float* __restrict__ outb,
                                              const int* __restrict__ start,
                                              float* __restrict__ pooled) {
    int g = blockIdx.x;
    int f = threadIdx.x;
    int n0 = start[g], n1 = start[g + 1];
    float s = 0.f;
    for (int n = n0; n < n1; ++n) s += outb[n * HH + f];
    pooled[g * HH + f] = s;
}

// ---------------- batchnorm stats -> scale/shift ----------------
__global__ __launch_bounds__(512) void k_bn(const float* __restrict__ pooled,
                                            const float* __restrict__ gamma,
                                            const float* __restrict__ beta,
                                            float* __restrict__ scale,
                                            float* __restrict__ shift) {
    __shared__ float sm[512], sm2[512];
    int f = threadIdx.x & 127, q = threadIdx.x >> 7;
    float s = 0.f, ss = 0.f;
    for (int g = q; g < GG; g += 4) {
        float v = pooled[g * HH + f];
        s += v;
        ss += v * v;
    }
    sm[threadIdx.x] = s;
    sm2[threadIdx.x] = ss;
    __syncthreads();
    if (q == 0) {
        s  = sm[f] + sm[f + 128] + sm[f + 256] + sm[f + 384];
        ss = sm2[f] + sm2[f + 128] + sm2[f + 256] + sm2[f + 384];
        float mean = s / GG;
        float var  = ss / GG - mean * mean;  // biased (jnp.var default)
        float sc = gamma[f] * rsqrtf(var + BN_EPS);
        scale[f] = sc;
        shift[f] = beta[f] - mean * sc;
    }
}

// ---------------- head: BN affine -> fc1+relu -> fc2 -> log_softmax --------
__global__ __launch_bounds__(128) void k_head(const float* __restrict__ pooled,
                                              const float* __restrict__ scale,
                                              const float* __restrict__ shift,
                                              const float* __restrict__ fc1w,
                                              const float* __restrict__ fc1b,
                                              const float* __restrict__ fc2w,
                                              const float* __restrict__ fc2b,
                                              float* __restrict__ out) {
    __shared__ __align__(16) float xb[128];
    __shared__ __align__(16) float h1[128];
    __shared__ float lg[16];
    int g = blockIdx.x;
    int t = threadIdx.x;
    xb[t] = pooled[g * HH + t] * scale[t] + shift[t];
    __syncthreads();
    float acc = 0.f;
    const float4* wr = reinterpret_cast<const float4*>(&fc1w[t * HH]);
    #pragma unroll 8
    for (int k = 0; k < 32; ++k) {
        float4 w4 = wr[k];
        float4 xv = *reinterpret_cast<const float4*>(&xb[k * 4]);
        acc += w4.x * xv.x + w4.y * xv.y + w4.z * xv.z + w4.w * xv.w;
    }
    acc += fc1b[t];
    h1[t] = (acc > 0.f) ? acc : 0.f;
    __syncthreads();
    if (t < CC) {
        float a = 0.f;
        const float4* w2 = reinterpret_cast<const float4*>(&fc2w[t * HH]);
        #pragma unroll 8
        for (int k = 0; k < 32; ++k) {
            float4 w4 = w2[k];
            float4 hv = *reinterpret_cast<const float4*>(&h1[k * 4]);
            a += w4.x * hv.x + w4.y * hv.y + w4.z * hv.z + w4.w * hv.w;
        }
        lg[t] = a + fc2b[t];
    }
    __syncthreads();
    if (t == 0) {
        float mx = lg[0];
        for (int c = 1; c < CC; ++c) mx = fmaxf(mx, lg[c]);
        float se = 0.f;
        for (int c = 0; c < CC; ++c) se += __expf(lg[c] - mx);
        float lse = mx + logf(se);
        for (int c = 0; c < CC; ++c) out[g * CC + c] = lg[c] - lse;
    }
}

// ---------------- launch ----------------
extern "C" void kernel_launch(void* const* d_in, const int* in_sizes, int n_in,
                              void* d_out, int out_size, void* d_ws, size_t ws_size,
                              hipStream_t stream) {
    const float* x_in  = (const float*)d_in[0];
    const int*   eidx  = (const int*)d_in[1];
    const int*   src   = eidx;
    const int*   dst   = eidx + NE;
    const int*   idx   = (const int*)d_in[2];
    const float* fc_w  = (const float*)d_in[3];
    const float* a1    = (const float*)d_in[4];
    const float* a2    = (const float*)d_in[5];
    const float* fc1w  = (const float*)d_in[6];
    const float* fc1b  = (const float*)d_in[7];
    const float* fc2w  = (const float*)d_in[8];
    const float* fc2b  = (const float*)d_in[9];
    const float* gamma = (const float*)d_in[10];
    const float* beta  = (const float*)d_in[11];
    float* out = (float*)d_out;

    char* p = (char*)d_ws;
    auto alloc = [&](size_t bytes) {
        char* r = p;
        p += (bytes + 255) & ~(size_t)255;
        return r;
    };
    double* st     = (double*)alloc(4 * sizeof(double));
    float*  wsum   = (float*)alloc(HH * sizeof(float));
    float*  musig  = (float*)alloc(4 * sizeof(float));
    float*  scale  = (float*)alloc(HH * sizeof(float));
    float*  shift  = (float*)alloc(HH * sizeof(float));
    int*    cnt    = (int*)alloc(NN * sizeof(int));
    int*    off    = (int*)alloc((NN + 1) * sizeof(int));
    int*    cursor = (int*)alloc(NN * sizeof(int));
    int*    start  = (int*)alloc((GG + 1) * sizeof(int));
    int*    dst_s  = (int*)alloc((size_t)NE * sizeof(int));
    float*  z      = (float*)alloc((size_t)NN * HH * sizeof(float));
    float*  outb   = (float*)alloc((size_t)NN * HH * sizeof(float));
    float*  s1     = (float*)alloc(NN * sizeof(float));
    float*  s2     = (float*)alloc(NN * sizeof(float));
    float*  pooled = (float*)alloc((size_t)GG * HH * sizeof(float));

    hipMemsetAsync(st, 0, 4 * sizeof(double), stream);
    hipMemsetAsync(cnt, 0, NN * sizeof(int), stream);

    k_stats<<<1024, 256, 0, stream>>>(x_in, st);
    k_finalize<<<1, 128, 0, stream>>>(fc_w, st, wsum, musig);
    k_hist<<<(NE + 255) / 256, 256, 0, stream>>>(src, cnt);
    k_scan<<<1, 1024, 0, stream>>>(cnt, off, cursor);
    k_gemm<<<(NN + 63) / 64, 256, 0, stream>>>(x_in, fc_w, wsum, musig, z);
    k_s1s2<<<(NN * 64) / 256, 256, 0, stream>>>(z, a1, a2, s1, s2);
    k_scatter<<<(NE + 255) / 256, 256, 0, stream>>>(src, dst, cursor, dst_s);
    k_aggregate<<<(NN * 64) / 256, 256, 0, stream>>>(z, s1, s2, off, dst_s, outb);
    k_bounds<<<(NN + 1 + 255) / 256, 256, 0, stream>>>(idx, start);
    k_pool<<<GG, 128, 0, stream>>>(outb, start, pooled);
    k_bn<<<1, 512, 0, stream>>>(pooled, gamma, beta, scale, shift);
    k_head<<<GG, 128, 0, stream>>>(pooled, scale, shift, fc1w, fc1b, fc2w, fc2b, out);
}

// Round 4
// 518.581 us; speedup vs baseline: 1.3297x; 1.3297x over previous
//
#include <hip/hip_runtime.h>

#define NN 50000
#define NE 1600000
#define DD 128
#define HH 128
#define CC 10
#define GG 512
#define LRELU_A 0.05f
#define BN_EPS 1e-5f

typedef unsigned int u32;
typedef unsigned short u16;

__device__ __forceinline__ u16 f2bf(float f) {
    u32 u = __float_as_uint(f);
    u32 r = u + 0x7FFFu + ((u >> 16) & 1u);
    return (u16)(r >> 16);
}

// ---------------- stats: global sum & sumsq of x_in ----------------
__global__ __launch_bounds__(256) void k_stats(const float* __restrict__ x,
                                               double* __restrict__ st) {
    const int M4 = NN * DD / 4;
    double s = 0.0, ss = 0.0;
    for (int i = blockIdx.x * blockDim.x + threadIdx.x; i < M4;
         i += gridDim.x * blockDim.x) {
        float4 v = reinterpret_cast<const float4*>(x)[i];
        s  += (double)v.x + (double)v.y + (double)v.z + (double)v.w;
        ss += (double)v.x * v.x + (double)v.y * v.y + (double)v.z * v.z +
              (double)v.w * v.w;
    }
    for (int d = 32; d; d >>= 1) { s += __shfl_down(s, d); ss += __shfl_down(ss, d); }
    __shared__ double ls[4], lss[4];
    int lane = threadIdx.x & 63, w = threadIdx.x >> 6;
    if (lane == 0) { ls[w] = s; lss[w] = ss; }
    __syncthreads();
    if (threadIdx.x == 0) {
        s  = ls[0] + ls[1] + ls[2] + ls[3];
        ss = lss[0] + lss[1] + lss[2] + lss[3];
        atomicAdd(&st[0], s);
        atomicAdd(&st[1], ss);
    }
}

// ---------------- finalize stats + per-output-row weight sums ----------------
__global__ __launch_bounds__(128) void k_finalize(const float* __restrict__ fc_w,
                                                  const double* __restrict__ st,
                                                  float* __restrict__ wsum,
                                                  float* __restrict__ musig) {
    int c = threadIdx.x;
    float s = 0.f;
    for (int k = 0; k < DD; ++k) s += fc_w[c * DD + k];
    wsum[c] = s;
    if (c == 0) {
        double M = (double)NN * DD;
        double mean = st[0] / M;
        double var  = (st[1] - st[0] * st[0] / M) / (M - 1.0);  // ddof=1
        musig[0] = (float)mean;
        musig[1] = (float)(1.0 / sqrt(var));
    }
}

// ---------------- transpose fc_w -> wt[k][c] (global, 64 KB) ----------------
__global__ __launch_bounds__(256) void k_wt(const float* __restrict__ w,
                                            float* __restrict__ wt) {
    int i = blockIdx.x * 256 + threadIdx.x;  // i = k*128 + c
    int k = i >> 7, c = i & 127;
    wt[i] = w[c * DD + k];
}

// ---------------- edge histogram by src ----------------
__global__ __launch_bounds__(256) void k_hist(const int* __restrict__ src,
                                              int* __restrict__ cnt) {
    int e = blockIdx.x * 256 + threadIdx.x;
    if (e < NE) atomicAdd(&cnt[src[e]], 1);
}

// ---------------- single-block scan -> CSR offsets ----------------
__global__ __launch_bounds__(1024) void k_scan(const int* __restrict__ cnt,
                                               int* __restrict__ off,
                                               int* __restrict__ cursor) {
    __shared__ int part[1024];
    const int CH = (NN + 1023) / 1024;  // 49
    int t = threadIdx.x;
    int base = t * CH;
    int s = 0;
    for (int i = 0; i < CH; ++i)
        if (base + i < NN) s += cnt[base + i];
    part[t] = s;
    __syncthreads();
    for (int d = 1; d < 1024; d <<= 1) {
        int v = 0;
        if (t >= d) v = part[t - d];
        __syncthreads();
        if (t >= d) part[t] += v;
        __syncthreads();
    }
    int run = part[t] - s;  // exclusive prefix of this chunk
    for (int i = 0; i < CH; ++i) {
        int n = base + i;
        if (n < NN) {
            off[n] = run;
            cursor[n] = run;
            run += cnt[n];
        }
    }
    if (t == 1023) off[NN] = part[1023];
}

// ------ z = x_std @ fc_w^T, fused: z fp32, z bf16, s1=z@a1, s2=z@a2 ------
#define PADX 132
__global__ __launch_bounds__(256, 4) void k_gemm(const float* __restrict__ x,
                                                 const float* __restrict__ wt,
                                                 const float* __restrict__ wsum,
                                                 const float* __restrict__ musig,
                                                 const float* __restrict__ a1,
                                                 const float* __restrict__ a2,
                                                 float* __restrict__ z,
                                                 u32* __restrict__ zbf,
                                                 float* __restrict__ s1,
                                                 float* __restrict__ s2) {
    __shared__ float xs[64][PADX];  // ~34 KB -> 4 blocks/CU
    int tid = threadIdx.x;
    int row0 = blockIdx.x * 64;

    for (int i = tid; i < 64 * 32; i += 256) {
        int r = i >> 5;
        int m = i & 31;
        int gr = row0 + r;
        float4 v = (gr < NN) ? reinterpret_cast<const float4*>(x)[gr * 32 + m]
                             : make_float4(0.f, 0.f, 0.f, 0.f);
        *reinterpret_cast<float4*>(&xs[r][m << 2]) = v;
    }
    __syncthreads();

    int trow = tid >> 4, tcol = tid & 15;
    float acc[4][8];
    #pragma unroll
    for (int i = 0; i < 4; ++i)
        #pragma unroll
        for (int j = 0; j < 8; ++j) acc[i][j] = 0.f;

    const float4* wt4 = reinterpret_cast<const float4*>(wt);
    for (int k = 0; k < 128; k += 4) {
        float4 xv[4];
        #pragma unroll
        for (int i = 0; i < 4; ++i)
            xv[i] = *reinterpret_cast<const float4*>(&xs[trow * 4 + i][k]);
        #pragma unroll
        for (int kk = 0; kk < 4; ++kk) {
            float4 w0 = wt4[(k + kk) * 32 + tcol * 2];
            float4 w1 = wt4[(k + kk) * 32 + tcol * 2 + 1];
            #pragma unroll
            for (int i = 0; i < 4; ++i) {
                float a = (kk == 0) ? xv[i].x
                        : (kk == 1) ? xv[i].y
                        : (kk == 2) ? xv[i].z : xv[i].w;
                acc[i][0] += a * w0.x; acc[i][1] += a * w0.y;
                acc[i][2] += a * w0.z; acc[i][3] += a * w0.w;
                acc[i][4] += a * w1.x; acc[i][5] += a * w1.y;
                acc[i][6] += a * w1.z; acc[i][7] += a * w1.w;
            }
        }
    }

    float mu = musig[0], isig = musig[1];
    int c0 = tcol * 8;
    float4 a10 = *reinterpret_cast<const float4*>(&a1[c0]);
    float4 a11 = *reinterpret_cast<const float4*>(&a1[c0 + 4]);
    float4 a20 = *reinterpret_cast<const float4*>(&a2[c0]);
    float4 a21 = *reinterpret_cast<const float4*>(&a2[c0 + 4]);
    float ws0x = wsum[c0 + 0], ws0y = wsum[c0 + 1], ws0z = wsum[c0 + 2], ws0w = wsum[c0 + 3];
    float ws1x = wsum[c0 + 4], ws1y = wsum[c0 + 5], ws1z = wsum[c0 + 6], ws1w = wsum[c0 + 7];

    float p1[4], p2[4];
    #pragma unroll
    for (int i = 0; i < 4; ++i) {
        int gr = row0 + trow * 4 + i;
        float4 o0, o1;
        o0.x = (acc[i][0] - mu * ws0x) * isig;
        o0.y = (acc[i][1] - mu * ws0y) * isig;
        o0.z = (acc[i][2] - mu * ws0z) * isig;
        o0.w = (acc[i][3] - mu * ws0w) * isig;
        o1.x = (acc[i][4] - mu * ws1x) * isig;
        o1.y = (acc[i][5] - mu * ws1y) * isig;
        o1.z = (acc[i][6] - mu * ws1z) * isig;
        o1.w = (acc[i][7] - mu * ws1w) * isig;
        p1[i] = o0.x * a10.x + o0.y * a10.y + o0.z * a10.z + o0.w * a10.w +
                o1.x * a11.x + o1.y * a11.y + o1.z * a11.z + o1.w * a11.w;
        p2[i] = o0.x * a20.x + o0.y * a20.y + o0.z * a20.z + o0.w * a20.w +
                o1.x * a21.x + o1.y * a21.y + o1.z * a21.z + o1.w * a21.w;
        if (gr < NN) {
            *reinterpret_cast<float4*>(&z[gr * HH + c0]) = o0;
            *reinterpret_cast<float4*>(&z[gr * HH + c0 + 4]) = o1;
            uint4 pk;
            pk.x = ((u32)f2bf(o0.y) << 16) | f2bf(o0.x);
            pk.y = ((u32)f2bf(o0.w) << 16) | f2bf(o0.z);
            pk.z = ((u32)f2bf(o1.y) << 16) | f2bf(o1.x);
            pk.w = ((u32)f2bf(o1.w) << 16) | f2bf(o1.z);
            // row = 128 bf16 = 64 u32; thread covers u32 [tcol*4, tcol*4+4)
            *reinterpret_cast<uint4*>(&zbf[gr * 64 + tcol * 4]) = pk;
        }
    }
    // reduce p1/p2 across the 16 tcol lanes (same trow group)
    #pragma unroll
    for (int d = 8; d; d >>= 1) {
        #pragma unroll
        for (int i = 0; i < 4; ++i) {
            p1[i] += __shfl_down(p1[i], d, 16);
            p2[i] += __shfl_down(p2[i], d, 16);
        }
    }
    if (tcol == 0) {
        #pragma unroll
        for (int i = 0; i < 4; ++i) {
            int gr = row0 + trow * 4 + i;
            if (gr < NN) { s1[gr] = p1[i]; s2[gr] = p2[i]; }
        }
    }
}

// ---------------- scatter edges into CSR order (store dst only) ----------------
__global__ __launch_bounds__(256) void k_scatter(const int* __restrict__ src,
                                                 const int* __restrict__ dst,
                                                 int* __restrict__ cursor,
                                                 int* __restrict__ dst_s) {
    int e = blockIdx.x * 256 + threadIdx.x;
    if (e < NE) {
        int p = atomicAdd(&cursor[src[e]], 1);
        dst_s[p] = dst[e];
    }
}

// --- aggregate: relu(softmax-weighted sum of z_bf[dst]) -> atomic pool ---
__global__ __launch_bounds__(256) void k_aggregate(const u32* __restrict__ zbf,
                                                   const float* __restrict__ s1,
                                                   const float* __restrict__ s2,
                                                   const int* __restrict__ off,
                                                   const int* __restrict__ dst_s,
                                                   const int* __restrict__ idx,
                                                   float* __restrict__ pooled) {
    int node = (blockIdx.x * 256 + threadIdx.x) >> 6;
    int lane = threadIdx.x & 63;
    if (node >= NN) return;
    int j0 = off[node], j1 = off[node + 1];
    float s1n = s1[node];
    float acc0 = 0.f, acc1 = 0.f, hs = 0.f;
    int j = j0;
    for (; j + 4 <= j1; j += 4) {
        int d0 = dst_s[j], d1 = dst_s[j + 1], d2 = dst_s[j + 2], d3 = dst_s[j + 3];
        float e0 = s1n + s2[d0], e1 = s1n + s2[d1];
        float e2 = s1n + s2[d2], e3 = s1n + s2[d3];
        u32 u0 = zbf[d0 * 64 + lane];
        u32 u1 = zbf[d1 * 64 + lane];
        u32 u2 = zbf[d2 * 64 + lane];
        u32 u3 = zbf[d3 * 64 + lane];
        e0 = (e0 >= 0.f) ? e0 : LRELU_A * e0;
        e1 = (e1 >= 0.f) ? e1 : LRELU_A * e1;
        e2 = (e2 >= 0.f) ? e2 : LRELU_A * e2;
        e3 = (e3 >= 0.f) ? e3 : LRELU_A * e3;
        float h0 = __expf(e0), h1 = __expf(e1), h2 = __expf(e2), h3 = __expf(e3);
        hs += (h0 + h1) + (h2 + h3);
        acc0 += h0 * __uint_as_float(u0 << 16) + h1 * __uint_as_float(u1 << 16) +
                h2 * __uint_as_float(u2 << 16) + h3 * __uint_as_float(u3 << 16);
        acc1 += h0 * __uint_as_float(u0 & 0xFFFF0000u) +
                h1 * __uint_as_float(u1 & 0xFFFF0000u) +
                h2 * __uint_as_float(u2 & 0xFFFF0000u) +
                h3 * __uint_as_float(u3 & 0xFFFF0000u);
    }
    for (; j < j1; ++j) {
        int d = dst_s[j];
        float ev = s1n + s2[d];
        ev = (ev >= 0.f) ? ev : LRELU_A * ev;
        float h = __expf(ev);
        u32 u = zbf[d * 64 + lane];
        acc0 += h * __uint_as_float(u << 16);
        acc1 += h * __uint_as_float(u & 0xFFFF0000u);
        hs += h;
    }
    float inv = (hs > 0.f) ? 1.f / hs : 0.f;
    float o0 = fmaxf(acc0 * inv, 0.f);
    float o1 = fmaxf(acc1 * inv, 0.f);
    int g = idx[node];
    atomicAdd(&pooled[g * HH + lane * 2], o0);
    atomicAdd(&pooled[g * HH + lane * 2 + 1], o1);
}

// ---------------- batchnorm stats -> scale/shift ----------------
__global__ __launch_bounds__(512) void k_bn(const float* __restrict__ pooled,
                                            const float* __restrict__ gamma,
                                            const float* __restrict__ beta,
                                            float* __restrict__ scale,
                                            float* __restrict__ shift) {
    __shared__ float sm[512], sm2[512];
    int f = threadIdx.x & 127, q = threadIdx.x >> 7;
    float s = 0.f, ss = 0.f;
    for (int g = q; g < GG; g += 4) {
        float v = pooled[g * HH + f];
        s += v;
        ss += v * v;
    }
    sm[threadIdx.x] = s;
    sm2[threadIdx.x] = ss;
    __syncthreads();
    if (q == 0) {
        s  = sm[f] + sm[f + 128] + sm[f + 256] + sm[f + 384];
        ss = sm2[f] + sm2[f + 128] + sm2[f + 256] + sm2[f + 384];
        float mean = s / GG;
        float var  = ss / GG - mean * mean;  // biased (jnp.var default)
        float sc = gamma[f] * rsqrtf(var + BN_EPS);
        scale[f] = sc;
        shift[f] = beta[f] - mean * sc;
    }
}

// ---------------- head: BN affine -> fc1+relu -> fc2 -> log_softmax --------
__global__ __launch_bounds__(128) void k_head(const float* __restrict__ pooled,
                                              const float* __restrict__ scale,
                                              const float* __restrict__ shift,
                                              const float* __restrict__ fc1w,
                                              const float* __restrict__ fc1b,
                                              const float* __restrict__ fc2w,
                                              const float* __restrict__ fc2b,
                                              float* __restrict__ out) {
    __shared__ __align__(16) float xb[128];
    __shared__ __align__(16) float h1[128];
    __shared__ float lg[16];
    int g = blockIdx.x;
    int t = threadIdx.x;
    xb[t] = pooled[g * HH + t] * scale[t] + shift[t];
    __syncthreads();
    float acc = 0.f;
    const float4* wr = reinterpret_cast<const float4*>(&fc1w[t * HH]);
    #pragma unroll 8
    for (int k = 0; k < 32; ++k) {
        float4 w4 = wr[k];
        float4 xv = *reinterpret_cast<const float4*>(&xb[k * 4]);
        acc += w4.x * xv.x + w4.y * xv.y + w4.z * xv.z + w4.w * xv.w;
    }
    acc += fc1b[t];
    h1[t] = (acc > 0.f) ? acc : 0.f;
    __syncthreads();
    if (t < CC) {
        float a = 0.f;
        const float4* w2 = reinterpret_cast<const float4*>(&fc2w[t * HH]);
        #pragma unroll 8
        for (int k = 0; k < 32; ++k) {
            float4 w4 = w2[k];
            float4 hv = *reinterpret_cast<const float4*>(&h1[k * 4]);
            a += w4.x * hv.x + w4.y * hv.y + w4.z * hv.z + w4.w * hv.w;
        }
        lg[t] = a + fc2b[t];
    }
    __syncthreads();
    if (t == 0) {
        float mx = lg[0];
        for (int c = 1; c < CC; ++c) mx = fmaxf(mx, lg[c]);
        float se = 0.f;
        for (int c = 0; c < CC; ++c) se += __expf(lg[c] - mx);
        float lse = mx + logf(se);
        for (int c = 0; c < CC; ++c) out[g * CC + c] = lg[c] - lse;
    }
}

// ---------------- launch ----------------
extern "C" void kernel_launch(void* const* d_in, const int* in_sizes, int n_in,
                              void* d_out, int out_size, void* d_ws, size_t ws_size,
                              hipStream_t stream) {
    const float* x_in  = (const float*)d_in[0];
    const int*   eidx  = (const int*)d_in[1];
    const int*   src   = eidx;
    const int*   dst   = eidx + NE;
    const int*   idx   = (const int*)d_in[2];
    const float* fc_w  = (const float*)d_in[3];
    const float* a1    = (const float*)d_in[4];
    const float* a2    = (const float*)d_in[5];
    const float* fc1w  = (const float*)d_in[6];
    const float* fc1b  = (const float*)d_in[7];
    const float* fc2w  = (const float*)d_in[8];
    const float* fc2b  = (const float*)d_in[9];
    const float* gamma = (const float*)d_in[10];
    const float* beta  = (const float*)d_in[11];
    float* out = (float*)d_out;

    char* p = (char*)d_ws;
    auto alloc = [&](size_t bytes) {
        char* r = p;
        p += (bytes + 255) & ~(size_t)255;
        return r;
    };
    double* st     = (double*)alloc(4 * sizeof(double));
    float*  wsum   = (float*)alloc(HH * sizeof(float));
    float*  musig  = (float*)alloc(4 * sizeof(float));
    float*  scale  = (float*)alloc(HH * sizeof(float));
    float*  shift  = (float*)alloc(HH * sizeof(float));
    float*  wt     = (float*)alloc((size_t)DD * HH * sizeof(float));
    int*    cnt    = (int*)alloc(NN * sizeof(int));
    int*    off    = (int*)alloc((NN + 1) * sizeof(int));
    int*    cursor = (int*)alloc(NN * sizeof(int));
    int*    dst_s  = (int*)alloc((size_t)NE * sizeof(int));
    float*  z      = (float*)alloc((size_t)NN * HH * sizeof(float));
    u32*    zbf    = (u32*)alloc((size_t)NN * (HH / 2) * sizeof(u32));
    float*  s1     = (float*)alloc(NN * sizeof(float));
    float*  s2     = (float*)alloc(NN * sizeof(float));
    float*  pooled = (float*)alloc((size_t)GG * HH * sizeof(float));

    hipMemsetAsync(st, 0, 4 * sizeof(double), stream);
    hipMemsetAsync(cnt, 0, NN * sizeof(int), stream);
    hipMemsetAsync(pooled, 0, (size_t)GG * HH * sizeof(float), stream);

    k_stats<<<1024, 256, 0, stream>>>(x_in, st);
    k_finalize<<<1, 128, 0, stream>>>(fc_w, st, wsum, musig);
    k_wt<<<(DD * HH) / 256, 256, 0, stream>>>(fc_w, wt);
    k_hist<<<(NE + 255) / 256, 256, 0, stream>>>(src, cnt);
    k_scan<<<1, 1024, 0, stream>>>(cnt, off, cursor);
    k_gemm<<<(NN + 63) / 64, 256, 0, stream>>>(x_in, wt, wsum, musig, a1, a2,
                                               z, zbf, s1, s2);
    k_scatter<<<(NE + 255) / 256, 256, 0, stream>>>(src, dst, cursor, dst_s);
    k_aggregate<<<(NN * 64) / 256, 256, 0, stream>>>(zbf, s1, s2, off, dst_s,
                                                     idx, pooled);
    k_bn<<<1, 512, 0, stream>>>(pooled, gamma, beta, scale, shift);
    k_head<<<GG, 128, 0, stream>>>(pooled, scale, shift, fc1w, fc1b, fc2w, fc2b, out);
}

// Round 5
// 356.209 us; speedup vs baseline: 1.9358x; 1.4558x over previous
//
#include <hip/hip_runtime.h>

#define NN 50000
#define NE 1600000
#define DD 128
#define HH 128
#define CC 10
#define GG 512
#define LRELU_A 0.05f
#define BN_EPS 1e-5f

#define TT 256          // tiles for counting sort
#define EPT (NE / TT)   // 6250 edges per tile
#define HALF 25000      // node half-range per LDS pass

typedef unsigned int u32;
typedef unsigned short u16;

__device__ __forceinline__ u16 f2bf(float f) {
    u32 u = __float_as_uint(f);
    u32 r = u + 0x7FFFu + ((u >> 16) & 1u);
    return (u16)(r >> 16);
}

// ---------------- stats: global sum & sumsq of x_in ----------------
__global__ __launch_bounds__(256) void k_stats(const float* __restrict__ x,
                                               double* __restrict__ st) {
    const int M4 = NN * DD / 4;
    double s = 0.0, ss = 0.0;
    for (int i = blockIdx.x * blockDim.x + threadIdx.x; i < M4;
         i += gridDim.x * blockDim.x) {
        float4 v = reinterpret_cast<const float4*>(x)[i];
        s  += (double)v.x + (double)v.y + (double)v.z + (double)v.w;
        ss += (double)v.x * v.x + (double)v.y * v.y + (double)v.z * v.z +
              (double)v.w * v.w;
    }
    for (int d = 32; d; d >>= 1) { s += __shfl_down(s, d); ss += __shfl_down(ss, d); }
    __shared__ double ls[4], lss[4];
    int lane = threadIdx.x & 63, w = threadIdx.x >> 6;
    if (lane == 0) { ls[w] = s; lss[w] = ss; }
    __syncthreads();
    if (threadIdx.x == 0) {
        s  = ls[0] + ls[1] + ls[2] + ls[3];
        ss = lss[0] + lss[1] + lss[2] + lss[3];
        atomicAdd(&st[0], s);
        atomicAdd(&st[1], ss);
    }
}

// ---------------- finalize stats + per-output-row weight sums ----------------
__global__ __launch_bounds__(128) void k_finalize(const float* __restrict__ fc_w,
                                                  const double* __restrict__ st,
                                                  float* __restrict__ wsum,
                                                  float* __restrict__ musig) {
    int c = threadIdx.x;
    float s = 0.f;
    for (int k = 0; k < DD; ++k) s += fc_w[c * DD + k];
    wsum[c] = s;
    if (c == 0) {
        double M = (double)NN * DD;
        double mean = st[0] / M;
        double var  = (st[1] - st[0] * st[0] / M) / (M - 1.0);  // ddof=1
        musig[0] = (float)mean;
        musig[1] = (float)(1.0 / sqrt(var));
    }
}

// ---------------- transpose fc_w -> wt[k][c] (global, 64 KB) ----------------
__global__ __launch_bounds__(256) void k_wt(const float* __restrict__ w,
                                            float* __restrict__ wt) {
    int i = blockIdx.x * 256 + threadIdx.x;  // i = k*128 + c
    int k = i >> 7, c = i & 127;
    wt[i] = w[c * DD + k];
}

// ------- tile histogram: cnt_t[t][n] = #edges of tile t with src==n -------
// LDS: 2 x u16 packed per u32 over a 25000-node half-range (50 KB).
__global__ __launch_bounds__(256) void k_thist(const int* __restrict__ src,
                                               u16* __restrict__ cnt_t) {
    __shared__ u32 h[HALF / 2];
    int t = blockIdx.x, tid = threadIdx.x;
    int e0 = t * EPT;
    int s[25];
    #pragma unroll
    for (int i = 0; i < 25; ++i) {
        int el = i * 256 + tid;
        s[i] = (el < EPT) ? src[e0 + el] : -1;
    }
    for (int half = 0; half < 2; ++half) {
        int lo = half * HALF;
        for (int i = tid; i < HALF / 2; i += 256) h[i] = 0;
        __syncthreads();
        #pragma unroll
        for (int i = 0; i < 25; ++i) {
            int n = s[i] - lo;
            if (n >= 0 && n < HALF)
                atomicAdd(&h[n >> 1], (n & 1) ? 65536u : 1u);
        }
        __syncthreads();
        u32* out = reinterpret_cast<u32*>(cnt_t + (size_t)t * NN + lo);
        for (int i = tid; i < HALF / 2; i += 256) out[i] = h[i];
        __syncthreads();
    }
}

// ------- per-node prefix over tiles: rel[t][n], cnt[n] = total degree -------
__global__ __launch_bounds__(256) void k_rel(const u16* __restrict__ cnt_t,
                                             u16* __restrict__ rel,
                                             int* __restrict__ cnt) {
    int n = blockIdx.x * 256 + threadIdx.x;
    if (n >= NN) return;
    int run = 0;
    for (int t = 0; t < TT; ++t) {
        int c = cnt_t[(size_t)t * NN + n];
        rel[(size_t)t * NN + n] = (u16)run;
        run += c;
    }
    cnt[n] = run;
}

// ---------------- single-block scan -> CSR offsets ----------------
__global__ __launch_bounds__(1024) void k_scan(const int* __restrict__ cnt,
                                               int* __restrict__ off) {
    __shared__ int part[1024];
    const int CH = (NN + 1023) / 1024;  // 49
    int t = threadIdx.x;
    int base = t * CH;
    int s = 0;
    for (int i = 0; i < CH; ++i)
        if (base + i < NN) s += cnt[base + i];
    part[t] = s;
    __syncthreads();
    for (int d = 1; d < 1024; d <<= 1) {
        int v = 0;
        if (t >= d) v = part[t - d];
        __syncthreads();
        if (t >= d) part[t] += v;
        __syncthreads();
    }
    int run = part[t] - s;  // exclusive prefix of this chunk
    for (int i = 0; i < CH; ++i) {
        int n = base + i;
        if (n < NN) {
            off[n] = run;
            run += cnt[n];
        }
    }
    if (t == 1023) off[NN] = part[1023];
}

// ------- scatter (atomic-free): slot = off[n] + rel[t][n] + LDS local rank ---
__global__ __launch_bounds__(256) void k_scatter2(const int* __restrict__ src,
                                                  const int* __restrict__ dst,
                                                  const int* __restrict__ off,
                                                  const u16* __restrict__ rel,
                                                  int* __restrict__ dst_s) {
    __shared__ u32 h[HALF / 2];
    int t = blockIdx.x, tid = threadIdx.x;
    int e0 = t * EPT;
    int s[25], d[25];
    #pragma unroll
    for (int i = 0; i < 25; ++i) {
        int el = i * 256 + tid;
        if (el < EPT) { s[i] = src[e0 + el]; d[i] = dst[e0 + el]; }
        else s[i] = -1;
    }
    const u16* relt = rel + (size_t)t * NN;
    for (int half = 0; half < 2; ++half) {
        int lo = half * HALF;
        for (int i = tid; i < HALF / 2; i += 256) h[i] = 0;
        __syncthreads();
        #pragma unroll
        for (int i = 0; i < 25; ++i) {
            int n = s[i] - lo;
            if (n >= 0 && n < HALF) {
                u32 old = atomicAdd(&h[n >> 1], (n & 1) ? 65536u : 1u);
                int lrank = (n & 1) ? (int)(old >> 16) : (int)(old & 0xFFFFu);
                int node = s[i];
                int p = off[node] + (int)relt[node] + lrank;
                dst_s[p] = d[i];
            }
        }
        __syncthreads();
    }
}

// ------ z = x_std @ fc_w^T, fused: z bf16, s1=z@a1, s2=z@a2 ------
#define PADX 132
__global__ __launch_bounds__(256, 4) void k_gemm(const float* __restrict__ x,
                                                 const float* __restrict__ wt,
                                                 const float* __restrict__ wsum,
                                                 const float* __restrict__ musig,
                                                 const float* __restrict__ a1,
                                                 const float* __restrict__ a2,
                                                 u32* __restrict__ zbf,
                                                 float* __restrict__ s1,
                                                 float* __restrict__ s2) {
    __shared__ float xs[64][PADX];  // ~34 KB -> 4 blocks/CU
    int tid = threadIdx.x;
    int row0 = blockIdx.x * 64;

    for (int i = tid; i < 64 * 32; i += 256) {
        int r = i >> 5;
        int m = i & 31;
        int gr = row0 + r;
        float4 v = (gr < NN) ? reinterpret_cast<const float4*>(x)[gr * 32 + m]
                             : make_float4(0.f, 0.f, 0.f, 0.f);
        *reinterpret_cast<float4*>(&xs[r][m << 2]) = v;
    }
    __syncthreads();

    int trow = tid >> 4, tcol = tid & 15;
    float acc[4][8];
    #pragma unroll
    for (int i = 0; i < 4; ++i)
        #pragma unroll
        for (int j = 0; j < 8; ++j) acc[i][j] = 0.f;

    const float4* wt4 = reinterpret_cast<const float4*>(wt);
    for (int k = 0; k < 128; k += 4) {
        float4 xv[4];
        #pragma unroll
        for (int i = 0; i < 4; ++i)
            xv[i] = *reinterpret_cast<const float4*>(&xs[trow * 4 + i][k]);
        #pragma unroll
        for (int kk = 0; kk < 4; ++kk) {
            float4 w0 = wt4[(k + kk) * 32 + tcol * 2];
            float4 w1 = wt4[(k + kk) * 32 + tcol * 2 + 1];
            #pragma unroll
            for (int i = 0; i < 4; ++i) {
                float a = (kk == 0) ? xv[i].x
                        : (kk == 1) ? xv[i].y
                        : (kk == 2) ? xv[i].z : xv[i].w;
                acc[i][0] += a * w0.x; acc[i][1] += a * w0.y;
                acc[i][2] += a * w0.z; acc[i][3] += a * w0.w;
                acc[i][4] += a * w1.x; acc[i][5] += a * w1.y;
                acc[i][6] += a * w1.z; acc[i][7] += a * w1.w;
            }
        }
    }

    float mu = musig[0], isig = musig[1];
    int c0 = tcol * 8;
    float4 a10 = *reinterpret_cast<const float4*>(&a1[c0]);
    float4 a11 = *reinterpret_cast<const float4*>(&a1[c0 + 4]);
    float4 a20 = *reinterpret_cast<const float4*>(&a2[c0]);
    float4 a21 = *reinterpret_cast<const float4*>(&a2[c0 + 4]);
    float ws0x = wsum[c0 + 0], ws0y = wsum[c0 + 1], ws0z = wsum[c0 + 2], ws0w = wsum[c0 + 3];
    float ws1x = wsum[c0 + 4], ws1y = wsum[c0 + 5], ws1z = wsum[c0 + 6], ws1w = wsum[c0 + 7];

    float p1[4], p2[4];
    #pragma unroll
    for (int i = 0; i < 4; ++i) {
        int gr = row0 + trow * 4 + i;
        float4 o0, o1;
        o0.x = (acc[i][0] - mu * ws0x) * isig;
        o0.y = (acc[i][1] - mu * ws0y) * isig;
        o0.z = (acc[i][2] - mu * ws0z) * isig;
        o0.w = (acc[i][3] - mu * ws0w) * isig;
        o1.x = (acc[i][4] - mu * ws1x) * isig;
        o1.y = (acc[i][5] - mu * ws1y) * isig;
        o1.z = (acc[i][6] - mu * ws1z) * isig;
        o1.w = (acc[i][7] - mu * ws1w) * isig;
        p1[i] = o0.x * a10.x + o0.y * a10.y + o0.z * a10.z + o0.w * a10.w +
                o1.x * a11.x + o1.y * a11.y + o1.z * a11.z + o1.w * a11.w;
        p2[i] = o0.x * a20.x + o0.y * a20.y + o0.z * a20.z + o0.w * a20.w +
                o1.x * a21.x + o1.y * a21.y + o1.z * a21.z + o1.w * a21.w;
        if (gr < NN) {
            uint4 pk;
            pk.x = ((u32)f2bf(o0.y) << 16) | f2bf(o0.x);
            pk.y = ((u32)f2bf(o0.w) << 16) | f2bf(o0.z);
            pk.z = ((u32)f2bf(o1.y) << 16) | f2bf(o1.x);
            pk.w = ((u32)f2bf(o1.w) << 16) | f2bf(o1.z);
            // row = 128 bf16 = 64 u32; thread covers u32 [tcol*4, tcol*4+4)
            *reinterpret_cast<uint4*>(&zbf[gr * 64 + tcol * 4]) = pk;
        }
    }
    // reduce p1/p2 across the 16 tcol lanes (same trow group)
    #pragma unroll
    for (int d = 8; d; d >>= 1) {
        #pragma unroll
        for (int i = 0; i < 4; ++i) {
            p1[i] += __shfl_down(p1[i], d, 16);
            p2[i] += __shfl_down(p2[i], d, 16);
        }
    }
    if (tcol == 0) {
        #pragma unroll
        for (int i = 0; i < 4; ++i) {
            int gr = row0 + trow * 4 + i;
            if (gr < NN) { s1[gr] = p1[i]; s2[gr] = p2[i]; }
        }
    }
}

// --- aggregate: relu(softmax-weighted sum of z_bf[dst]) -> atomic pool ---
__global__ __launch_bounds__(256) void k_aggregate(const u32* __restrict__ zbf,
                                                   const float* __restrict__ s1,
                                                   const float* __restrict__ s2,
                                                   const int* __restrict__ off,
                                                   const int* __restrict__ dst_s,
                                                   const int* __restrict__ idx,
                                                   float* __restrict__ pooled) {
    int node = (blockIdx.x * 256 + threadIdx.x) >> 6;
    int lane = threadIdx.x & 63;
    if (node >= NN) return;
    int j0 = off[node], j1 = off[node + 1];
    float s1n = s1[node];
    float acc0 = 0.f, acc1 = 0.f, hs = 0.f;
    int j = j0;
    for (; j + 4 <= j1; j += 4) {
        int d0 = dst_s[j], d1 = dst_s[j + 1], d2 = dst_s[j + 2], d3 = dst_s[j + 3];
        float e0 = s1n + s2[d0], e1 = s1n + s2[d1];
        float e2 = s1n + s2[d2], e3 = s1n + s2[d3];
        u32 u0 = zbf[d0 * 64 + lane];
        u32 u1 = zbf[d1 * 64 + lane];
        u32 u2 = zbf[d2 * 64 + lane];
        u32 u3 = zbf[d3 * 64 + lane];
        e0 = (e0 >= 0.f) ? e0 : LRELU_A * e0;
        e1 = (e1 >= 0.f) ? e1 : LRELU_A * e1;
        e2 = (e2 >= 0.f) ? e2 : LRELU_A * e2;
        e3 = (e3 >= 0.f) ? e3 : LRELU_A * e3;
        float h0 = __expf(e0), h1 = __expf(e1), h2 = __expf(e2), h3 = __expf(e3);
        hs += (h0 + h1) + (h2 + h3);
        acc0 += h0 * __uint_as_float(u0 << 16) + h1 * __uint_as_float(u1 << 16) +
                h2 * __uint_as_float(u2 << 16) + h3 * __uint_as_float(u3 << 16);
        acc1 += h0 * __uint_as_float(u0 & 0xFFFF0000u) +
                h1 * __uint_as_float(u1 & 0xFFFF0000u) +
                h2 * __uint_as_float(u2 & 0xFFFF0000u) +
                h3 * __uint_as_float(u3 & 0xFFFF0000u);
    }
    for (; j < j1; ++j) {
        int d = dst_s[j];
        float ev = s1n + s2[d];
        ev = (ev >= 0.f) ? ev : LRELU_A * ev;
        float h = __expf(ev);
        u32 u = zbf[d * 64 + lane];
        acc0 += h * __uint_as_float(u << 16);
        acc1 += h * __uint_as_float(u & 0xFFFF0000u);
        hs += h;
    }
    float inv = (hs > 0.f) ? 1.f / hs : 0.f;
    float o0 = fmaxf(acc0 * inv, 0.f);
    float o1 = fmaxf(acc1 * inv, 0.f);
    int g = idx[node];
    atomicAdd(&pooled[g * HH + lane * 2], o0);
    atomicAdd(&pooled[g * HH + lane * 2 + 1], o1);
}

// ---------------- batchnorm stats -> scale/shift ----------------
__global__ __launch_bounds__(512) void k_bn(const float* __restrict__ pooled,
                                            const float* __restrict__ gamma,
                                            const float* __restrict__ beta,
                                            float* __restrict__ scale,
                                            float* __restrict__ shift) {
    __shared__ float sm[512], sm2[512];
    int f = threadIdx.x & 127, q = threadIdx.x >> 7;
    float s = 0.f, ss = 0.f;
    for (int g = q; g < GG; g += 4) {
        float v = pooled[g * HH + f];
        s += v;
        ss += v * v;
    }
    sm[threadIdx.x] = s;
    sm2[threadIdx.x] = ss;
    __syncthreads();
    if (q == 0) {
        s  = sm[f] + sm[f + 128] + sm[f + 256] + sm[f + 384];
        ss = sm2[f] + sm2[f + 128] + sm2[f + 256] + sm2[f + 384];
        float mean = s / GG;
        float var  = ss / GG - mean * mean;  // biased (jnp.var default)
        float sc = gamma[f] * rsqrtf(var + BN_EPS);
        scale[f] = sc;
        shift[f] = beta[f] - mean * sc;
    }
}

// ---------------- head: BN affine -> fc1+relu -> fc2 -> log_softmax --------
__global__ __launch_bounds__(128) void k_head(const float* __restrict__ pooled,
                                              const float* __restrict__ scale,
                                              const float* __restrict__ shift,
                                              const float* __restrict__ fc1w,
                                              const float* __restrict__ fc1b,
                                              const float* __restrict__ fc2w,
                                              const float* __restrict__ fc2b,
                                              float* __restrict__ out) {
    __shared__ __align__(16) float xb[128];
    __shared__ __align__(16) float h1[128];
    __shared__ float lg[16];
    int g = blockIdx.x;
    int t = threadIdx.x;
    xb[t] = pooled[g * HH + t] * scale[t] + shift[t];
    __syncthreads();
    float acc = 0.f;
    const float4* wr = reinterpret_cast<const float4*>(&fc1w[t * HH]);
    #pragma unroll 8
    for (int k = 0; k < 32; ++k) {
        float4 w4 = wr[k];
        float4 xv = *reinterpret_cast<const float4*>(&xb[k * 4]);
        acc += w4.x * xv.x + w4.y * xv.y + w4.z * xv.z + w4.w * xv.w;
    }
    acc += fc1b[t];
    h1[t] = (acc > 0.f) ? acc : 0.f;
    __syncthreads();
    if (t < CC) {
        float a = 0.f;
        const float4* w2 = reinterpret_cast<const float4*>(&fc2w[t * HH]);
        #pragma unroll 8
        for (int k = 0; k < 32; ++k) {
            float4 w4 = w2[k];
            float4 hv = *reinterpret_cast<const float4*>(&h1[k * 4]);
            a += w4.x * hv.x + w4.y * hv.y + w4.z * hv.z + w4.w * hv.w;
        }
        lg[t] = a + fc2b[t];
    }
    __syncthreads();
    if (t == 0) {
        float mx = lg[0];
        for (int c = 1; c < CC; ++c) mx = fmaxf(mx, lg[c]);
        float se = 0.f;
        for (int c = 0; c < CC; ++c) se += __expf(lg[c] - mx);
        float lse = mx + logf(se);
        for (int c = 0; c < CC; ++c) out[g * CC + c] = lg[c] - lse;
    }
}

// ---------------- launch ----------------
extern "C" void kernel_launch(void* const* d_in, const int* in_sizes, int n_in,
                              void* d_out, int out_size, void* d_ws, size_t ws_size,
                              hipStream_t stream) {
    const float* x_in  = (const float*)d_in[0];
    const int*   eidx  = (const int*)d_in[1];
    const int*   src   = eidx;
    const int*   dst   = eidx + NE;
    const int*   idx   = (const int*)d_in[2];
    const float* fc_w  = (const float*)d_in[3];
    const float* a1    = (const float*)d_in[4];
    const float* a2    = (const float*)d_in[5];
    const float* fc1w  = (const float*)d_in[6];
    const float* fc1b  = (const float*)d_in[7];
    const float* fc2w  = (const float*)d_in[8];
    const float* fc2b  = (const float*)d_in[9];
    const float* gamma = (const float*)d_in[10];
    const float* beta  = (const float*)d_in[11];
    float* out = (float*)d_out;

    char* p = (char*)d_ws;
    auto alloc = [&](size_t bytes) {
        char* r = p;
        p += (bytes + 255) & ~(size_t)255;
        return r;
    };
    double* st     = (double*)alloc(4 * sizeof(double));
    float*  wsum   = (float*)alloc(HH * sizeof(float));
    float*  musig  = (float*)alloc(4 * sizeof(float));
    float*  scale  = (float*)alloc(HH * sizeof(float));
    float*  shift  = (float*)alloc(HH * sizeof(float));
    float*  wt     = (float*)alloc((size_t)DD * HH * sizeof(float));
    u16*    cnt_t  = (u16*)alloc((size_t)TT * NN * sizeof(u16));
    u16*    rel    = (u16*)alloc((size_t)TT * NN * sizeof(u16));
    int*    cnt    = (int*)alloc(NN * sizeof(int));
    int*    off    = (int*)alloc((NN + 1) * sizeof(int));
    int*    dst_s  = (int*)alloc((size_t)NE * sizeof(int));
    u32*    zbf    = (u32*)alloc((size_t)NN * (HH / 2) * sizeof(u32));
    float*  s1     = (float*)alloc(NN * sizeof(float));
    float*  s2     = (float*)alloc(NN * sizeof(float));
    float*  pooled = (float*)alloc((size_t)GG * HH * sizeof(float));

    hipMemsetAsync(st, 0, 4 * sizeof(double), stream);
    hipMemsetAsync(pooled, 0, (size_t)GG * HH * sizeof(float), stream);

    k_stats<<<1024, 256, 0, stream>>>(x_in, st);
    k_finalize<<<1, 128, 0, stream>>>(fc_w, st, wsum, musig);
    k_wt<<<(DD * HH) / 256, 256, 0, stream>>>(fc_w, wt);
    k_thist<<<TT, 256, 0, stream>>>(src, cnt_t);
    k_rel<<<(NN + 255) / 256, 256, 0, stream>>>(cnt_t, rel, cnt);
    k_scan<<<1, 1024, 0, stream>>>(cnt, off);
    k_gemm<<<(NN + 63) / 64, 256, 0, stream>>>(x_in, wt, wsum, musig, a1, a2,
                                               zbf, s1, s2);
    k_scatter2<<<TT, 256, 0, stream>>>(src, dst, off, rel, dst_s);
    k_aggregate<<<(NN * 64) / 256, 256, 0, stream>>>(zbf, s1, s2, off, dst_s,
                                                     idx, pooled);
    k_bn<<<1, 512, 0, stream>>>(pooled, gamma, beta, scale, shift);
    k_head<<<GG, 128, 0, stream>>>(pooled, scale, shift, fc1w, fc1b, fc2w, fc2b, out);
}

// Round 6
// 275.165 us; speedup vs baseline: 2.5059x; 1.2945x over previous
//
#include <hip/hip_runtime.h>

#define NN 50000
#define NE 1600000
#define DD 128
#define HH 128
#define CC 10
#define GG 512
#define LRELU_A 0.05f
#define BN_EPS 1e-5f

#define TT 256          // tiles for counting sort
#define EPT (NE / TT)   // 6250 edges per tile
#define HALF 25000      // node half-range per LDS pass
#define SB ((NN + 255) / 256)  // 196 scan blocks

typedef unsigned int u32;
typedef unsigned short u16;

__device__ __forceinline__ u16 f2bf(float f) {
    u32 u = __float_as_uint(f);
    u32 r = u + 0x7FFFu + ((u >> 16) & 1u);
    return (u16)(r >> 16);
}

// ---------------- stats: global sum & sumsq of x_in ----------------
__global__ __launch_bounds__(256) void k_stats(const float* __restrict__ x,
                                               double* __restrict__ st) {
    const int M4 = NN * DD / 4;
    double s = 0.0, ss = 0.0;
    for (int i = blockIdx.x * blockDim.x + threadIdx.x; i < M4;
         i += gridDim.x * blockDim.x) {
        float4 v = reinterpret_cast<const float4*>(x)[i];
        s  += (double)v.x + (double)v.y + (double)v.z + (double)v.w;
        ss += (double)v.x * v.x + (double)v.y * v.y + (double)v.z * v.z +
              (double)v.w * v.w;
    }
    for (int d = 32; d; d >>= 1) { s += __shfl_down(s, d); ss += __shfl_down(ss, d); }
    __shared__ double ls[4], lss[4];
    int lane = threadIdx.x & 63, w = threadIdx.x >> 6;
    if (lane == 0) { ls[w] = s; lss[w] = ss; }
    __syncthreads();
    if (threadIdx.x == 0) {
        s  = ls[0] + ls[1] + ls[2] + ls[3];
        ss = lss[0] + lss[1] + lss[2] + lss[3];
        atomicAdd(&st[0], s);
        atomicAdd(&st[1], ss);
    }
}

// ---------------- finalize stats + per-output-row weight sums ----------------
__global__ __launch_bounds__(128) void k_finalize(const float* __restrict__ fc_w,
                                                  const double* __restrict__ st,
                                                  float* __restrict__ wsum,
                                                  float* __restrict__ musig) {
    int c = threadIdx.x;
    float s = 0.f;
    for (int k = 0; k < DD; ++k) s += fc_w[c * DD + k];
    wsum[c] = s;
    if (c == 0) {
        double M = (double)NN * DD;
        double mean = st[0] / M;
        double var  = (st[1] - st[0] * st[0] / M) / (M - 1.0);  // ddof=1
        musig[0] = (float)mean;
        musig[1] = (float)(1.0 / sqrt(var));
    }
}

// ---------------- transpose fc_w -> wt[k][c] (global, 64 KB) ----------------
__global__ __launch_bounds__(256) void k_wt(const float* __restrict__ w,
                                            float* __restrict__ wt) {
    int i = blockIdx.x * 256 + threadIdx.x;  // i = k*128 + c
    int k = i >> 7, c = i & 127;
    wt[i] = w[c * DD + k];
}

// ------- tile histogram: cnt_t[t][n] = #edges of tile t with src==n -------
// LDS: 2 x u16 packed per u32 over a 25000-node half-range (50 KB).
__global__ __launch_bounds__(256) void k_thist(const int* __restrict__ src,
                                               u16* __restrict__ cnt_t) {
    __shared__ u32 h[HALF / 2];
    int t = blockIdx.x, tid = threadIdx.x;
    int e0 = t * EPT;
    int s[25];
    #pragma unroll
    for (int i = 0; i < 25; ++i) {
        int el = i * 256 + tid;
        s[i] = (el < EPT) ? src[e0 + el] : -1;
    }
    for (int half = 0; half < 2; ++half) {
        int lo = half * HALF;
        for (int i = tid; i < HALF / 2; i += 256) h[i] = 0;
        __syncthreads();
        #pragma unroll
        for (int i = 0; i < 25; ++i) {
            int n = s[i] - lo;
            if (n >= 0 && n < HALF)
                atomicAdd(&h[n >> 1], (n & 1) ? 65536u : 1u);
        }
        __syncthreads();
        u32* out = reinterpret_cast<u32*>(cnt_t + (size_t)t * NN + lo);
        for (int i = tid; i < HALF / 2; i += 256) out[i] = h[i];
        __syncthreads();
    }
}

// --- per-node prefix over tiles: rel[t][n]; block-local scan of degrees ---
// off[n] = exclusive prefix within block; part[b] = block total.
__global__ __launch_bounds__(256) void k_rel(const u16* __restrict__ cnt_t,
                                             u16* __restrict__ rel,
                                             int* __restrict__ off,
                                             int* __restrict__ part) {
    int b = blockIdx.x, t = threadIdx.x;
    int n = b * 256 + t;
    int run = 0;
    if (n < NN) {
        for (int tt = 0; tt < TT; ++tt) {
            int c = cnt_t[(size_t)tt * NN + n];
            rel[(size_t)tt * NN + n] = (u16)run;
            run += c;
        }
    }
    __shared__ int sm[256];
    sm[t] = run;
    __syncthreads();
    int v = run;
    for (int d = 1; d < 256; d <<= 1) {
        int x = 0;
        if (t >= d) x = sm[t - d];
        __syncthreads();
        if (t >= d) sm[t] += x;
        __syncthreads();
    }
    if (n < NN) off[n] = sm[t] - v;  // block-exclusive prefix
    if (t == 255) part[b] = sm[255];
}

// ---------------- scan the 196 block partials (one tiny block) ----------------
__global__ __launch_bounds__(256) void k_scan2(int* __restrict__ part) {
    __shared__ int sm[256];
    int t = threadIdx.x;
    int v = (t < SB) ? part[t] : 0;
    sm[t] = v;
    __syncthreads();
    for (int d = 1; d < 256; d <<= 1) {
        int x = 0;
        if (t >= d) x = sm[t - d];
        __syncthreads();
        if (t >= d) sm[t] += x;
        __syncthreads();
    }
    if (t < SB) part[t] = sm[t] - v;  // exclusive
}

// ---------------- uniform add: off[n] += part[b]; off[NN] = NE ----------------
__global__ __launch_bounds__(256) void k_add(int* __restrict__ off,
                                             const int* __restrict__ part) {
    int b = blockIdx.x, t = threadIdx.x;
    int n = b * 256 + t;
    if (n < NN) off[n] += part[b];
    if (b == 0 && t == 0) off[NN] = NE;
}

// ------- scatter (atomic-free): slot = off[n] + rel[t][n] + LDS local rank ---
__global__ __launch_bounds__(256) void k_scatter2(const int* __restrict__ src,
                                                  const int* __restrict__ dst,
                                                  const int* __restrict__ off,
                                                  const u16* __restrict__ rel,
                                                  int* __restrict__ dst_s) {
    __shared__ u32 h[HALF / 2];
    int t = blockIdx.x, tid = threadIdx.x;
    int e0 = t * EPT;
    int s[25], d[25];
    #pragma unroll
    for (int i = 0; i < 25; ++i) {
        int el = i * 256 + tid;
        if (el < EPT) { s[i] = src[e0 + el]; d[i] = dst[e0 + el]; }
        else s[i] = -1;
    }
    const u16* relt = rel + (size_t)t * NN;
    for (int half = 0; half < 2; ++half) {
        int lo = half * HALF;
        for (int i = tid; i < HALF / 2; i += 256) h[i] = 0;
        __syncthreads();
        #pragma unroll
        for (int i = 0; i < 25; ++i) {
            int n = s[i] - lo;
            if (n >= 0 && n < HALF) {
                u32 old = atomicAdd(&h[n >> 1], (n & 1) ? 65536u : 1u);
                int lrank = (n & 1) ? (int)(old >> 16) : (int)(old & 0xFFFFu);
                int node = s[i];
                int p = off[node] + (int)relt[node] + lrank;
                dst_s[p] = d[i];
            }
        }
        __syncthreads();
    }
}

// ------ z = x_std @ fc_w^T, fused: z bf16, s1=z@a1, s2=z@a2 ------
#define PADX 132
__global__ __launch_bounds__(256, 4) void k_gemm(const float* __restrict__ x,
                                                 const float* __restrict__ wt,
                                                 const float* __restrict__ wsum,
                                                 const float* __restrict__ musig,
                                                 const float* __restrict__ a1,
                                                 const float* __restrict__ a2,
                                                 u32* __restrict__ zbf,
                                                 float* __restrict__ s1,
                                                 float* __restrict__ s2) {
    __shared__ float xs[64][PADX];  // ~34 KB -> 4 blocks/CU
    int tid = threadIdx.x;
    int row0 = blockIdx.x * 64;

    for (int i = tid; i < 64 * 32; i += 256) {
        int r = i >> 5;
        int m = i & 31;
        int gr = row0 + r;
        float4 v = (gr < NN) ? reinterpret_cast<const float4*>(x)[gr * 32 + m]
                             : make_float4(0.f, 0.f, 0.f, 0.f);
        *reinterpret_cast<float4*>(&xs[r][m << 2]) = v;
    }
    __syncthreads();

    int trow = tid >> 4, tcol = tid & 15;
    float acc[4][8];
    #pragma unroll
    for (int i = 0; i < 4; ++i)
        #pragma unroll
        for (int j = 0; j < 8; ++j) acc[i][j] = 0.f;

    const float4* wt4 = reinterpret_cast<const float4*>(wt);
    for (int k = 0; k < 128; k += 4) {
        float4 xv[4];
        #pragma unroll
        for (int i = 0; i < 4; ++i)
            xv[i] = *reinterpret_cast<const float4*>(&xs[trow * 4 + i][k]);
        #pragma unroll
        for (int kk = 0; kk < 4; ++kk) {
            float4 w0 = wt4[(k + kk) * 32 + tcol * 2];
            float4 w1 = wt4[(k + kk) * 32 + tcol * 2 + 1];
            #pragma unroll
            for (int i = 0; i < 4; ++i) {
                float a = (kk == 0) ? xv[i].x
                        : (kk == 1) ? xv[i].y
                        : (kk == 2) ? xv[i].z : xv[i].w;
                acc[i][0] += a * w0.x; acc[i][1] += a * w0.y;
                acc[i][2] += a * w0.z; acc[i][3] += a * w0.w;
                acc[i][4] += a * w1.x; acc[i][5] += a * w1.y;
                acc[i][6] += a * w1.z; acc[i][7] += a * w1.w;
            }
        }
    }

    float mu = musig[0], isig = musig[1];
    int c0 = tcol * 8;
    float4 a10 = *reinterpret_cast<const float4*>(&a1[c0]);
    float4 a11 = *reinterpret_cast<const float4*>(&a1[c0 + 4]);
    float4 a20 = *reinterpret_cast<const float4*>(&a2[c0]);
    float4 a21 = *reinterpret_cast<const float4*>(&a2[c0 + 4]);
    float ws0x = wsum[c0 + 0], ws0y = wsum[c0 + 1], ws0z = wsum[c0 + 2], ws0w = wsum[c0 + 3];
    float ws1x = wsum[c0 + 4], ws1y = wsum[c0 + 5], ws1z = wsum[c0 + 6], ws1w = wsum[c0 + 7];

    float p1[4], p2[4];
    #pragma unroll
    for (int i = 0; i < 4; ++i) {
        int gr = row0 + trow * 4 + i;
        float4 o0, o1;
        o0.x = (acc[i][0] - mu * ws0x) * isig;
        o0.y = (acc[i][1] - mu * ws0y) * isig;
        o0.z = (acc[i][2] - mu * ws0z) * isig;
        o0.w = (acc[i][3] - mu * ws0w) * isig;
        o1.x = (acc[i][4] - mu * ws1x) * isig;
        o1.y = (acc[i][5] - mu * ws1y) * isig;
        o1.z = (acc[i][6] - mu * ws1z) * isig;
        o1.w = (acc[i][7] - mu * ws1w) * isig;
        p1[i] = o0.x * a10.x + o0.y * a10.y + o0.z * a10.z + o0.w * a10.w +
                o1.x * a11.x + o1.y * a11.y + o1.z * a11.z + o1.w * a11.w;
        p2[i] = o0.x * a20.x + o0.y * a20.y + o0.z * a20.z + o0.w * a20.w +
                o1.x * a21.x + o1.y * a21.y + o1.z * a21.z + o1.w * a21.w;
        if (gr < NN) {
            uint4 pk;
            pk.x = ((u32)f2bf(o0.y) << 16) | f2bf(o0.x);
            pk.y = ((u32)f2bf(o0.w) << 16) | f2bf(o0.z);
            pk.z = ((u32)f2bf(o1.y) << 16) | f2bf(o1.x);
            pk.w = ((u32)f2bf(o1.w) << 16) | f2bf(o1.z);
            // row = 128 bf16 = 64 u32; thread covers u32 [tcol*4, tcol*4+4)
            *reinterpret_cast<uint4*>(&zbf[gr * 64 + tcol * 4]) = pk;
        }
    }
    // reduce p1/p2 across the 16 tcol lanes (same trow group)
    #pragma unroll
    for (int d = 8; d; d >>= 1) {
        #pragma unroll
        for (int i = 0; i < 4; ++i) {
            p1[i] += __shfl_down(p1[i], d, 16);
            p2[i] += __shfl_down(p2[i], d, 16);
        }
    }
    if (tcol == 0) {
        #pragma unroll
        for (int i = 0; i < 4; ++i) {
            int gr = row0 + trow * 4 + i;
            if (gr < NN) { s1[gr] = p1[i]; s2[gr] = p2[i]; }
        }
    }
}

// --- aggregate: relu(softmax-weighted sum of z_bf[dst]) -> atomic pool ---
__global__ __launch_bounds__(256) void k_aggregate(const u32* __restrict__ zbf,
                                                   const float* __restrict__ s1,
                                                   const float* __restrict__ s2,
                                                   const int* __restrict__ off,
                                                   const int* __restrict__ dst_s,
                                                   const int* __restrict__ idx,
                                                   float* __restrict__ pooled) {
    int node = (blockIdx.x * 256 + threadIdx.x) >> 6;
    int lane = threadIdx.x & 63;
    if (node >= NN) return;
    int j0 = off[node], j1 = off[node + 1];
    float s1n = s1[node];
    float acc0 = 0.f, acc1 = 0.f, hs = 0.f;
    int j = j0;
    for (; j + 4 <= j1; j += 4) {
        int d0 = dst_s[j], d1 = dst_s[j + 1], d2 = dst_s[j + 2], d3 = dst_s[j + 3];
        float e0 = s1n + s2[d0], e1 = s1n + s2[d1];
        float e2 = s1n + s2[d2], e3 = s1n + s2[d3];
        u32 u0 = zbf[d0 * 64 + lane];
        u32 u1 = zbf[d1 * 64 + lane];
        u32 u2 = zbf[d2 * 64 + lane];
        u32 u3 = zbf[d3 * 64 + lane];
        e0 = (e0 >= 0.f) ? e0 : LRELU_A * e0;
        e1 = (e1 >= 0.f) ? e1 : LRELU_A * e1;
        e2 = (e2 >= 0.f) ? e2 : LRELU_A * e2;
        e3 = (e3 >= 0.f) ? e3 : LRELU_A * e3;
        float h0 = __expf(e0), h1 = __expf(e1), h2 = __expf(e2), h3 = __expf(e3);
        hs += (h0 + h1) + (h2 + h3);
        acc0 += h0 * __uint_as_float(u0 << 16) + h1 * __uint_as_float(u1 << 16) +
                h2 * __uint_as_float(u2 << 16) + h3 * __uint_as_float(u3 << 16);
        acc1 += h0 * __uint_as_float(u0 & 0xFFFF0000u) +
                h1 * __uint_as_float(u1 & 0xFFFF0000u) +
                h2 * __uint_as_float(u2 & 0xFFFF0000u) +
                h3 * __uint_as_float(u3 & 0xFFFF0000u);
    }
    for (; j < j1; ++j) {
        int d = dst_s[j];
        float ev = s1n + s2[d];
        ev = (ev >= 0.f) ? ev : LRELU_A * ev;
        float h = __expf(ev);
        u32 u = zbf[d * 64 + lane];
        acc0 += h * __uint_as_float(u << 16);
        acc1 += h * __uint_as_float(u & 0xFFFF0000u);
        hs += h;
    }
    float inv = (hs > 0.f) ? 1.f / hs : 0.f;
    float o0 = fmaxf(acc0 * inv, 0.f);
    float o1 = fmaxf(acc1 * inv, 0.f);
    int g = idx[node];
    atomicAdd(&pooled[g * HH + lane * 2], o0);
    atomicAdd(&pooled[g * HH + lane * 2 + 1], o1);
}

// ---------------- batchnorm stats -> scale/shift ----------------
__global__ __launch_bounds__(512) void k_bn(const float* __restrict__ pooled,
                                            const float* __restrict__ gamma,
                                            const float* __restrict__ beta,
                                            float* __restrict__ scale,
                                            float* __restrict__ shift) {
    __shared__ float sm[512], sm2[512];
    int f = threadIdx.x & 127, q = threadIdx.x >> 7;
    float s = 0.f, ss = 0.f;
    for (int g = q; g < GG; g += 4) {
        float v = pooled[g * HH + f];
        s += v;
        ss += v * v;
    }
    sm[threadIdx.x] = s;
    sm2[threadIdx.x] = ss;
    __syncthreads();
    if (q == 0) {
        s  = sm[f] + sm[f + 128] + sm[f + 256] + sm[f + 384];
        ss = sm2[f] + sm2[f + 128] + sm2[f + 256] + sm2[f + 384];
        float mean = s / GG;
        float var  = ss / GG - mean * mean;  // biased (jnp.var default)
        float sc = gamma[f] * rsqrtf(var + BN_EPS);
        scale[f] = sc;
        shift[f] = beta[f] - mean * sc;
    }
}

// ---------------- head: BN affine -> fc1+relu -> fc2 -> log_softmax --------
__global__ __launch_bounds__(128) void k_head(const float* __restrict__ pooled,
                                              const float* __restrict__ scale,
                                              const float* __restrict__ shift,
                                              const float* __restrict__ fc1w,
                                              const float* __restrict__ fc1b,
                                              const float* __restrict__ fc2w,
                                              const float* __restrict__ fc2b,
                                              float* __restrict__ out) {
    __shared__ __align__(16) float xb[128];
    __shared__ __align__(16) float h1[128];
    __shared__ float lg[16];
    int g = blockIdx.x;
    int t = threadIdx.x;
    xb[t] = pooled[g * HH + t] * scale[t] + shift[t];
    __syncthreads();
    float acc = 0.f;
    const float4* wr = reinterpret_cast<const float4*>(&fc1w[t * HH]);
    #pragma unroll 8
    for (int k = 0; k < 32; ++k) {
        float4 w4 = wr[k];
        float4 xv = *reinterpret_cast<const float4*>(&xb[k * 4]);
        acc += w4.x * xv.x + w4.y * xv.y + w4.z * xv.z + w4.w * xv.w;
    }
    acc += fc1b[t];
    h1[t] = (acc > 0.f) ? acc : 0.f;
    __syncthreads();
    if (t < CC) {
        float a = 0.f;
        const float4* w2 = reinterpret_cast<const float4*>(&fc2w[t * HH]);
        #pragma unroll 8
        for (int k = 0; k < 32; ++k) {
            float4 w4 = w2[k];
            float4 hv = *reinterpret_cast<const float4*>(&h1[k * 4]);
            a += w4.x * hv.x + w4.y * hv.y + w4.z * hv.z + w4.w * hv.w;
        }
        lg[t] = a + fc2b[t];
    }
    __syncthreads();
    if (t == 0) {
        float mx = lg[0];
        for (int c = 1; c < CC; ++c) mx = fmaxf(mx, lg[c]);
        float se = 0.f;
        for (int c = 0; c < CC; ++c) se += __expf(lg[c] - mx);
        float lse = mx + logf(se);
        for (int c = 0; c < CC; ++c) out[g * CC + c] = lg[c] - lse;
    }
}

// ---------------- launch ----------------
extern "C" void kernel_launch(void* const* d_in, const int* in_sizes, int n_in,
                              void* d_out, int out_size, void* d_ws, size_t ws_size,
                              hipStream_t stream) {
    const float* x_in  = (const float*)d_in[0];
    const int*   eidx  = (const int*)d_in[1];
    const int*   src   = eidx;
    const int*   dst   = eidx + NE;
    const int*   idx   = (const int*)d_in[2];
    const float* fc_w  = (const float*)d_in[3];
    const float* a1    = (const float*)d_in[4];
    const float* a2    = (const float*)d_in[5];
    const float* fc1w  = (const float*)d_in[6];
    const float* fc1b  = (const float*)d_in[7];
    const float* fc2w  = (const float*)d_in[8];
    const float* fc2b  = (const float*)d_in[9];
    const float* gamma = (const float*)d_in[10];
    const float* beta  = (const float*)d_in[11];
    float* out = (float*)d_out;

    char* p = (char*)d_ws;
    auto alloc = [&](size_t bytes) {
        char* r = p;
        p += (bytes + 255) & ~(size_t)255;
        return r;
    };
    double* st     = (double*)alloc(4 * sizeof(double));
    float*  wsum   = (float*)alloc(HH * sizeof(float));
    float*  musig  = (float*)alloc(4 * sizeof(float));
    float*  scale  = (float*)alloc(HH * sizeof(float));
    float*  shift  = (float*)alloc(HH * sizeof(float));
    float*  wt     = (float*)alloc((size_t)DD * HH * sizeof(float));
    u16*    cnt_t  = (u16*)alloc((size_t)TT * NN * sizeof(u16));
    u16*    rel    = (u16*)alloc((size_t)TT * NN * sizeof(u16));
    int*    part   = (int*)alloc(SB * sizeof(int));
    int*    off    = (int*)alloc((NN + 1) * sizeof(int));
    int*    dst_s  = (int*)alloc((size_t)NE * sizeof(int));
    u32*    zbf    = (u32*)alloc((size_t)NN * (HH / 2) * sizeof(u32));
    float*  s1     = (float*)alloc(NN * sizeof(float));
    float*  s2     = (float*)alloc(NN * sizeof(float));
    float*  pooled = (float*)alloc((size_t)GG * HH * sizeof(float));

    hipMemsetAsync(st, 0, 4 * sizeof(double), stream);
    hipMemsetAsync(pooled, 0, (size_t)GG * HH * sizeof(float), stream);

    k_stats<<<1024, 256, 0, stream>>>(x_in, st);
    k_finalize<<<1, 128, 0, stream>>>(fc_w, st, wsum, musig);
    k_wt<<<(DD * HH) / 256, 256, 0, stream>>>(fc_w, wt);
    k_thist<<<TT, 256, 0, stream>>>(src, cnt_t);
    k_rel<<<SB, 256, 0, stream>>>(cnt_t, rel, off, part);
    k_scan2<<<1, 256, 0, stream>>>(part);
    k_add<<<SB, 256, 0, stream>>>(off, part);
    k_gemm<<<(NN + 63) / 64, 256, 0, stream>>>(x_in, wt, wsum, musig, a1, a2,
                                               zbf, s1, s2);
    k_scatter2<<<TT, 256, 0, stream>>>(src, dst, off, rel, dst_s);
    k_aggregate<<<(NN * 64) / 256, 256, 0, stream>>>(zbf, s1, s2, off, dst_s,
                                                     idx, pooled);
    k_bn<<<1, 512, 0, stream>>>(pooled, gamma, beta, scale, shift);
    k_head<<<GG, 128, 0, stream>>>(pooled, scale, shift, fc1w, fc1b, fc2w, fc2b, out);
}

// Round 7
// 247.571 us; speedup vs baseline: 2.7852x; 1.1115x over previous
//
#include <hip/hip_runtime.h>

#define NN 50000
#define NE 1600000
#define DD 128
#define HH 128
#define CC 10
#define GG 512
#define LRELU_A 0.05f
#define BN_EPS 1e-5f

#define TT 256          // tiles for counting sort
#define EPT (NE / TT)   // 6250 edges per tile
#define HALF 25000      // node half-range per LDS pass
#define SB ((NN + 255) / 256)  // 196 scan blocks
#define KNODE 8         // nodes per wave in aggregate

typedef unsigned int u32;
typedef unsigned short u16;

__device__ __forceinline__ u16 f2bf(float f) {
    u32 u = __float_as_uint(f);
    u32 r = u + 0x7FFFu + ((u >> 16) & 1u);
    return (u16)(r >> 16);
}

// ---------------- stats: global sum & sumsq of x_in ----------------
__global__ __launch_bounds__(256) void k_stats(const float* __restrict__ x,
                                               double* __restrict__ st) {
    const int M4 = NN * DD / 4;
    double s = 0.0, ss = 0.0;
    for (int i = blockIdx.x * blockDim.x + threadIdx.x; i < M4;
         i += gridDim.x * blockDim.x) {
        float4 v = reinterpret_cast<const float4*>(x)[i];
        s  += (double)v.x + (double)v.y + (double)v.z + (double)v.w;
        ss += (double)v.x * v.x + (double)v.y * v.y + (double)v.z * v.z +
              (double)v.w * v.w;
    }
    for (int d = 32; d; d >>= 1) { s += __shfl_down(s, d); ss += __shfl_down(ss, d); }
    __shared__ double ls[4], lss[4];
    int lane = threadIdx.x & 63, w = threadIdx.x >> 6;
    if (lane == 0) { ls[w] = s; lss[w] = ss; }
    __syncthreads();
    if (threadIdx.x == 0) {
        s  = ls[0] + ls[1] + ls[2] + ls[3];
        ss = lss[0] + lss[1] + lss[2] + lss[3];
        atomicAdd(&st[0], s);
        atomicAdd(&st[1], ss);
    }
}

// ---------------- finalize stats + per-output-row weight sums ----------------
__global__ __launch_bounds__(128) void k_finalize(const float* __restrict__ fc_w,
                                                  const double* __restrict__ st,
                                                  float* __restrict__ wsum,
                                                  float* __restrict__ musig) {
    int c = threadIdx.x;
    float s = 0.f;
    for (int k = 0; k < DD; ++k) s += fc_w[c * DD + k];
    wsum[c] = s;
    if (c == 0) {
        double M = (double)NN * DD;
        double mean = st[0] / M;
        double var  = (st[1] - st[0] * st[0] / M) / (M - 1.0);  // ddof=1
        musig[0] = (float)mean;
        musig[1] = (float)(1.0 / sqrt(var));
    }
}

// ---------------- transpose fc_w -> wt[k][c] (global, 64 KB) ----------------
__global__ __launch_bounds__(256) void k_wt(const float* __restrict__ w,
                                            float* __restrict__ wt) {
    int i = blockIdx.x * 256 + threadIdx.x;  // i = k*128 + c
    int k = i >> 7, c = i & 127;
    wt[i] = w[c * DD + k];
}

// ------- tile histogram: cnt_t[t][n] = #edges of tile t with src==n -------
// LDS: 2 x u16 packed per u32 over a 25000-node half-range (50 KB).
__global__ __launch_bounds__(256) void k_thist(const int* __restrict__ src,
                                               u16* __restrict__ cnt_t) {
    __shared__ u32 h[HALF / 2];
    int t = blockIdx.x, tid = threadIdx.x;
    int e0 = t * EPT;
    int s[25];
    #pragma unroll
    for (int i = 0; i < 25; ++i) {
        int el = i * 256 + tid;
        s[i] = (el < EPT) ? src[e0 + el] : -1;
    }
    for (int half = 0; half < 2; ++half) {
        int lo = half * HALF;
        for (int i = tid; i < HALF / 2; i += 256) h[i] = 0;
        __syncthreads();
        #pragma unroll
        for (int i = 0; i < 25; ++i) {
            int n = s[i] - lo;
            if (n >= 0 && n < HALF)
                atomicAdd(&h[n >> 1], (n & 1) ? 65536u : 1u);
        }
        __syncthreads();
        u32* out = reinterpret_cast<u32*>(cnt_t + (size_t)t * NN + lo);
        for (int i = tid; i < HALF / 2; i += 256) out[i] = h[i];
        __syncthreads();
    }
}

// --- per-node prefix over tiles: rel[t][n]; block-local scan of degrees ---
// off[n] = exclusive prefix within block; part[b] = block total.
__global__ __launch_bounds__(256) void k_rel(const u16* __restrict__ cnt_t,
                                             u16* __restrict__ rel,
                                             int* __restrict__ off,
                                             int* __restrict__ part) {
    int b = blockIdx.x, t = threadIdx.x;
    int n = b * 256 + t;
    int run = 0;
    if (n < NN) {
        for (int tt = 0; tt < TT; ++tt) {
            int c = cnt_t[(size_t)tt * NN + n];
            rel[(size_t)tt * NN + n] = (u16)run;
            run += c;
        }
    }
    __shared__ int sm[256];
    sm[t] = run;
    __syncthreads();
    int v = run;
    for (int d = 1; d < 256; d <<= 1) {
        int x = 0;
        if (t >= d) x = sm[t - d];
        __syncthreads();
        if (t >= d) sm[t] += x;
        __syncthreads();
    }
    if (n < NN) off[n] = sm[t] - v;  // block-exclusive prefix
    if (t == 255) part[b] = sm[255];
}

// ---------------- scan the 196 block partials (one tiny block) ----------------
__global__ __launch_bounds__(256) void k_scan2(int* __restrict__ part) {
    __shared__ int sm[256];
    int t = threadIdx.x;
    int v = (t < SB) ? part[t] : 0;
    sm[t] = v;
    __syncthreads();
    for (int d = 1; d < 256; d <<= 1) {
        int x = 0;
        if (t >= d) x = sm[t - d];
        __syncthreads();
        if (t >= d) sm[t] += x;
        __syncthreads();
    }
    if (t < SB) part[t] = sm[t] - v;  // exclusive
}

// ---------------- uniform add: off[n] += part[b]; off[NN] = NE ----------------
__global__ __launch_bounds__(256) void k_add(int* __restrict__ off,
                                             const int* __restrict__ part) {
    int b = blockIdx.x, t = threadIdx.x;
    int n = b * 256 + t;
    if (n < NN) off[n] += part[b];
    if (b == 0 && t == 0) off[NN] = NE;
}

// ------- scatter (atomic-free): slot = off[n] + rel[t][n] + LDS local rank ---
__global__ __launch_bounds__(256) void k_scatter2(const int* __restrict__ src,
                                                  const int* __restrict__ dst,
                                                  const int* __restrict__ off,
                                                  const u16* __restrict__ rel,
                                                  int* __restrict__ dst_s) {
    __shared__ u32 h[HALF / 2];
    int t = blockIdx.x, tid = threadIdx.x;
    int e0 = t * EPT;
    int s[25], d[25];
    #pragma unroll
    for (int i = 0; i < 25; ++i) {
        int el = i * 256 + tid;
        if (el < EPT) { s[i] = src[e0 + el]; d[i] = dst[e0 + el]; }
        else s[i] = -1;
    }
    const u16* relt = rel + (size_t)t * NN;
    for (int half = 0; half < 2; ++half) {
        int lo = half * HALF;
        for (int i = tid; i < HALF / 2; i += 256) h[i] = 0;
        __syncthreads();
        #pragma unroll
        for (int i = 0; i < 25; ++i) {
            int n = s[i] - lo;
            if (n >= 0 && n < HALF) {
                u32 old = atomicAdd(&h[n >> 1], (n & 1) ? 65536u : 1u);
                int lrank = (n & 1) ? (int)(old >> 16) : (int)(old & 0xFFFFu);
                int node = s[i];
                int p = off[node] + (int)relt[node] + lrank;
                dst_s[p] = d[i];
            }
        }
        __syncthreads();
    }
}

// ------ z = x_std @ fc_w^T, fused: z bf16, s1=z@a1, s2=z@a2 ------
#define PADX 132
__global__ __launch_bounds__(256, 4) void k_gemm(const float* __restrict__ x,
                                                 const float* __restrict__ wt,
                                                 const float* __restrict__ wsum,
                                                 const float* __restrict__ musig,
                                                 const float* __restrict__ a1,
                                                 const float* __restrict__ a2,
                                                 u32* __restrict__ zbf,
                                                 float* __restrict__ s1,
                                                 float* __restrict__ s2) {
    __shared__ float xs[64][PADX];  // ~34 KB -> 4 blocks/CU
    int tid = threadIdx.x;
    int row0 = blockIdx.x * 64;

    for (int i = tid; i < 64 * 32; i += 256) {
        int r = i >> 5;
        int m = i & 31;
        int gr = row0 + r;
        float4 v = (gr < NN) ? reinterpret_cast<const float4*>(x)[gr * 32 + m]
                             : make_float4(0.f, 0.f, 0.f, 0.f);
        *reinterpret_cast<float4*>(&xs[r][m << 2]) = v;
    }
    __syncthreads();

    int trow = tid >> 4, tcol = tid & 15;
    float acc[4][8];
    #pragma unroll
    for (int i = 0; i < 4; ++i)
        #pragma unroll
        for (int j = 0; j < 8; ++j) acc[i][j] = 0.f;

    const float4* wt4 = reinterpret_cast<const float4*>(wt);
    for (int k = 0; k < 128; k += 4) {
        float4 xv[4];
        #pragma unroll
        for (int i = 0; i < 4; ++i)
            xv[i] = *reinterpret_cast<const float4*>(&xs[trow * 4 + i][k]);
        #pragma unroll
        for (int kk = 0; kk < 4; ++kk) {
            float4 w0 = wt4[(k + kk) * 32 + tcol * 2];
            float4 w1 = wt4[(k + kk) * 32 + tcol * 2 + 1];
            #pragma unroll
            for (int i = 0; i < 4; ++i) {
                float a = (kk == 0) ? xv[i].x
                        : (kk == 1) ? xv[i].y
                        : (kk == 2) ? xv[i].z : xv[i].w;
                acc[i][0] += a * w0.x; acc[i][1] += a * w0.y;
                acc[i][2] += a * w0.z; acc[i][3] += a * w0.w;
                acc[i][4] += a * w1.x; acc[i][5] += a * w1.y;
                acc[i][6] += a * w1.z; acc[i][7] += a * w1.w;
            }
        }
    }

    float mu = musig[0], isig = musig[1];
    int c0 = tcol * 8;
    float4 a10 = *reinterpret_cast<const float4*>(&a1[c0]);
    float4 a11 = *reinterpret_cast<const float4*>(&a1[c0 + 4]);
    float4 a20 = *reinterpret_cast<const float4*>(&a2[c0]);
    float4 a21 = *reinterpret_cast<const float4*>(&a2[c0 + 4]);
    float ws0x = wsum[c0 + 0], ws0y = wsum[c0 + 1], ws0z = wsum[c0 + 2], ws0w = wsum[c0 + 3];
    float ws1x = wsum[c0 + 4], ws1y = wsum[c0 + 5], ws1z = wsum[c0 + 6], ws1w = wsum[c0 + 7];

    float p1[4], p2[4];
    #pragma unroll
    for (int i = 0; i < 4; ++i) {
        int gr = row0 + trow * 4 + i;
        float4 o0, o1;
        o0.x = (acc[i][0] - mu * ws0x) * isig;
        o0.y = (acc[i][1] - mu * ws0y) * isig;
        o0.z = (acc[i][2] - mu * ws0z) * isig;
        o0.w = (acc[i][3] - mu * ws0w) * isig;
        o1.x = (acc[i][4] - mu * ws1x) * isig;
        o1.y = (acc[i][5] - mu * ws1y) * isig;
        o1.z = (acc[i][6] - mu * ws1z) * isig;
        o1.w = (acc[i][7] - mu * ws1w) * isig;
        p1[i] = o0.x * a10.x + o0.y * a10.y + o0.z * a10.z + o0.w * a10.w +
                o1.x * a11.x + o1.y * a11.y + o1.z * a11.z + o1.w * a11.w;
        p2[i] = o0.x * a20.x + o0.y * a20.y + o0.z * a20.z + o0.w * a20.w +
                o1.x * a21.x + o1.y * a21.y + o1.z * a21.z + o1.w * a21.w;
        if (gr < NN) {
            uint4 pk;
            pk.x = ((u32)f2bf(o0.y) << 16) | f2bf(o0.x);
            pk.y = ((u32)f2bf(o0.w) << 16) | f2bf(o0.z);
            pk.z = ((u32)f2bf(o1.y) << 16) | f2bf(o1.x);
            pk.w = ((u32)f2bf(o1.w) << 16) | f2bf(o1.z);
            // row = 128 bf16 = 64 u32; thread covers u32 [tcol*4, tcol*4+4)
            *reinterpret_cast<uint4*>(&zbf[gr * 64 + tcol * 4]) = pk;
        }
    }
    // reduce p1/p2 across the 16 tcol lanes (same trow group)
    #pragma unroll
    for (int d = 8; d; d >>= 1) {
        #pragma unroll
        for (int i = 0; i < 4; ++i) {
            p1[i] += __shfl_down(p1[i], d, 16);
            p2[i] += __shfl_down(p2[i], d, 16);
        }
    }
    if (tcol == 0) {
        #pragma unroll
        for (int i = 0; i < 4; ++i) {
            int gr = row0 + trow * 4 + i;
            if (gr < NN) { s1[gr] = p1[i]; s2[gr] = p2[i]; }
        }
    }
}

// --- aggregate v2: lane-parallel h, broadcast FMA, register pooling ---
// One wave handles KNODE consecutive nodes (idx sorted -> same graph mostly).
__global__ __launch_bounds__(256) void k_aggregate(const u32* __restrict__ zbf,
                                                   const float* __restrict__ s1,
                                                   const float* __restrict__ s2,
                                                   const int* __restrict__ off,
                                                   const int* __restrict__ dst_s,
                                                   const int* __restrict__ idx,
                                                   float* __restrict__ pooled) {
    int wave = (blockIdx.x * 256 + threadIdx.x) >> 6;
    int lane = threadIdx.x & 63;
    int n0 = wave * KNODE;
    if (n0 >= NN) return;
    int n1 = n0 + KNODE;
    if (n1 > NN) n1 = NN;

    float pool0 = 0.f, pool1 = 0.f;
    int curg = idx[n0];

    for (int node = n0; node < n1; ++node) {
        int g = idx[node];
        if (g != curg) {
            atomicAdd(&pooled[curg * HH + lane * 2], pool0);
            atomicAdd(&pooled[curg * HH + lane * 2 + 1], pool1);
            pool0 = 0.f; pool1 = 0.f;
            curg = g;
        }
        int j0 = off[node], j1 = off[node + 1];
        float s1n = s1[node];
        float acc0 = 0.f, acc1 = 0.f, hsl = 0.f;

        for (int b = j0; b < j1; b += 64) {
            int cnt = j1 - b;
            if (cnt > 64) cnt = 64;
            // lane-parallel: lane l owns edge b+l
            int jj = b + ((lane < cnt) ? lane : 0);
            int dl = dst_s[jj];
            float ev = s1n + s2[dl];
            ev = (ev >= 0.f) ? ev : LRELU_A * ev;
            float hl = __expf(ev);
            if (lane >= cnt) hl = 0.f;
            hsl += hl;
            // broadcast loop: gather rows, FMA (uniform k -> v_readlane)
            int k = 0;
            for (; k + 4 <= cnt; k += 4) {
                int d0 = __shfl(dl, k),     d1 = __shfl(dl, k + 1);
                int d2 = __shfl(dl, k + 2), d3 = __shfl(dl, k + 3);
                float h0 = __shfl(hl, k),     h1 = __shfl(hl, k + 1);
                float h2 = __shfl(hl, k + 2), h3 = __shfl(hl, k + 3);
                u32 u0 = zbf[(d0 << 6) | lane];
                u32 u1 = zbf[(d1 << 6) | lane];
                u32 u2 = zbf[(d2 << 6) | lane];
                u32 u3 = zbf[(d3 << 6) | lane];
                acc0 += h0 * __uint_as_float(u0 << 16) +
                        h1 * __uint_as_float(u1 << 16) +
                        h2 * __uint_as_float(u2 << 16) +
                        h3 * __uint_as_float(u3 << 16);
                acc1 += h0 * __uint_as_float(u0 & 0xFFFF0000u) +
                        h1 * __uint_as_float(u1 & 0xFFFF0000u) +
                        h2 * __uint_as_float(u2 & 0xFFFF0000u) +
                        h3 * __uint_as_float(u3 & 0xFFFF0000u);
            }
            for (; k < cnt; ++k) {
                int dk = __shfl(dl, k);
                float hk = __shfl(hl, k);
                u32 u = zbf[(dk << 6) | lane];
                acc0 += hk * __uint_as_float(u << 16);
                acc1 += hk * __uint_as_float(u & 0xFFFF0000u);
            }
        }
        // wave-reduce the softmax denominator
        float hs = hsl;
        #pragma unroll
        for (int d = 32; d; d >>= 1) hs += __shfl_xor(hs, d);
        float inv = (hs > 0.f) ? 1.f / hs : 0.f;
        pool0 += fmaxf(acc0 * inv, 0.f);
        pool1 += fmaxf(acc1 * inv, 0.f);
    }
    atomicAdd(&pooled[curg * HH + lane * 2], pool0);
    atomicAdd(&pooled[curg * HH + lane * 2 + 1], pool1);
}

// ---------------- batchnorm stats -> scale/shift ----------------
__global__ __launch_bounds__(512) void k_bn(const float* __restrict__ pooled,
                                            const float* __restrict__ gamma,
                                            const float* __restrict__ beta,
                                            float* __restrict__ scale,
                                            float* __restrict__ shift) {
    __shared__ float sm[512], sm2[512];
    int f = threadIdx.x & 127, q = threadIdx.x >> 7;
    float s = 0.f, ss = 0.f;
    for (int g = q; g < GG; g += 4) {
        float v = pooled[g * HH + f];
        s += v;
        ss += v * v;
    }
    sm[threadIdx.x] = s;
    sm2[threadIdx.x] = ss;
    __syncthreads();
    if (q == 0) {
        s  = sm[f] + sm[f + 128] + sm[f + 256] + sm[f + 384];
        ss = sm2[f] + sm2[f + 128] + sm2[f + 256] + sm2[f + 384];
        float mean = s / GG;
        float var  = ss / GG - mean * mean;  // biased (jnp.var default)
        float sc = gamma[f] * rsqrtf(var + BN_EPS);
        scale[f] = sc;
        shift[f] = beta[f] - mean * sc;
    }
}

// ---------------- head: BN affine -> fc1+relu -> fc2 -> log_softmax --------
__global__ __launch_bounds__(128) void k_head(const float* __restrict__ pooled,
                                              const float* __restrict__ scale,
                                              const float* __restrict__ shift,
                                              const float* __restrict__ fc1w,
                                              const float* __restrict__ fc1b,
                                              const float* __restrict__ fc2w,
                                              const float* __restrict__ fc2b,
                                              float* __restrict__ out) {
    __shared__ __align__(16) float xb[128];
    __shared__ __align__(16) float h1[128];
    __shared__ float lg[16];
    int g = blockIdx.x;
    int t = threadIdx.x;
    xb[t] = pooled[g * HH + t] * scale[t] + shift[t];
    __syncthreads();
    float acc = 0.f;
    const float4* wr = reinterpret_cast<const float4*>(&fc1w[t * HH]);
    #pragma unroll 8
    for (int k = 0; k < 32; ++k) {
        float4 w4 = wr[k];
        float4 xv = *reinterpret_cast<const float4*>(&xb[k * 4]);
        acc += w4.x * xv.x + w4.y * xv.y + w4.z * xv.z + w4.w * xv.w;
    }
    acc += fc1b[t];
    h1[t] = (acc > 0.f) ? acc : 0.f;
    __syncthreads();
    if (t < CC) {
        float a = 0.f;
        const float4* w2 = reinterpret_cast<const float4*>(&fc2w[t * HH]);
        #pragma unroll 8
        for (int k = 0; k < 32; ++k) {
            float4 w4 = w2[k];
            float4 hv = *reinterpret_cast<const float4*>(&h1[k * 4]);
            a += w4.x * hv.x + w4.y * hv.y + w4.z * hv.z + w4.w * hv.w;
        }
        lg[t] = a + fc2b[t];
    }
    __syncthreads();
    if (t == 0) {
        float mx = lg[0];
        for (int c = 1; c < CC; ++c) mx = fmaxf(mx, lg[c]);
        float se = 0.f;
        for (int c = 0; c < CC; ++c) se += __expf(lg[c] - mx);
        float lse = mx + logf(se);
        for (int c = 0; c < CC; ++c) out[g * CC + c] = lg[c] - lse;
    }
}

// ---------------- launch ----------------
extern "C" void kernel_launch(void* const* d_in, const int* in_sizes, int n_in,
                              void* d_out, int out_size, void* d_ws, size_t ws_size,
                              hipStream_t stream) {
    const float* x_in  = (const float*)d_in[0];
    const int*   eidx  = (const int*)d_in[1];
    const int*   src   = eidx;
    const int*   dst   = eidx + NE;
    const int*   idx   = (const int*)d_in[2];
    const float* fc_w  = (const float*)d_in[3];
    const float* a1    = (const float*)d_in[4];
    const float* a2    = (const float*)d_in[5];
    const float* fc1w  = (const float*)d_in[6];
    const float* fc1b  = (const float*)d_in[7];
    const float* fc2w  = (const float*)d_in[8];
    const float* fc2b  = (const float*)d_in[9];
    const float* gamma = (const float*)d_in[10];
    const float* beta  = (const float*)d_in[11];
    float* out = (float*)d_out;

    char* p = (char*)d_ws;
    auto alloc = [&](size_t bytes) {
        char* r = p;
        p += (bytes + 255) & ~(size_t)255;
        return r;
    };
    double* st     = (double*)alloc(4 * sizeof(double));
    float*  wsum   = (float*)alloc(HH * sizeof(float));
    float*  musig  = (float*)alloc(4 * sizeof(float));
    float*  scale  = (float*)alloc(HH * sizeof(float));
    float*  shift  = (float*)alloc(HH * sizeof(float));
    float*  wt     = (float*)alloc((size_t)DD * HH * sizeof(float));
    u16*    cnt_t  = (u16*)alloc((size_t)TT * NN * sizeof(u16));
    u16*    rel    = (u16*)alloc((size_t)TT * NN * sizeof(u16));
    int*    part   = (int*)alloc(SB * sizeof(int));
    int*    off    = (int*)alloc((NN + 1) * sizeof(int));
    int*    dst_s  = (int*)alloc((size_t)NE * sizeof(int));
    u32*    zbf    = (u32*)alloc((size_t)NN * (HH / 2) * sizeof(u32));
    float*  s1     = (float*)alloc(NN * sizeof(float));
    float*  s2     = (float*)alloc(NN * sizeof(float));
    float*  pooled = (float*)alloc((size_t)GG * HH * sizeof(float));

    hipMemsetAsync(st, 0, 4 * sizeof(double), stream);
    hipMemsetAsync(pooled, 0, (size_t)GG * HH * sizeof(float), stream);

    k_stats<<<1024, 256, 0, stream>>>(x_in, st);
    k_finalize<<<1, 128, 0, stream>>>(fc_w, st, wsum, musig);
    k_wt<<<(DD * HH) / 256, 256, 0, stream>>>(fc_w, wt);
    k_thist<<<TT, 256, 0, stream>>>(src, cnt_t);
    k_rel<<<SB, 256, 0, stream>>>(cnt_t, rel, off, part);
    k_scan2<<<1, 256, 0, stream>>>(part);
    k_add<<<SB, 256, 0, stream>>>(off, part);
    k_gemm<<<(NN + 63) / 64, 256, 0, stream>>>(x_in, wt, wsum, musig, a1, a2,
                                               zbf, s1, s2);
    k_scatter2<<<TT, 256, 0, stream>>>(src, dst, off, rel, dst_s);
    int nwaves = (NN + KNODE - 1) / KNODE;          // 6250
    int nblocks = (nwaves + 3) / 4;                 // 4 waves per 256-thr block
    k_aggregate<<<nblocks, 256, 0, stream>>>(zbf, s1, s2, off, dst_s, idx, pooled);
    k_bn<<<1, 512, 0, stream>>>(pooled, gamma, beta, scale, shift);
    k_head<<<GG, 128, 0, stream>>>(pooled, scale, shift, fc1w, fc1b, fc2w, fc2b, out);
}